// Round 1
// baseline (1434.141 us; speedup 1.0000x reference)
//
#include <hip/hip_runtime.h>

#define N_DIN 128
#define N_DOUT 128

// ---------------- zero / relu helpers (float4 grid-stride) ----------------

__global__ __launch_bounds__(256) void zero_f4(float4* __restrict__ p, int n4) {
  int i = blockIdx.x * blockDim.x + threadIdx.x;
  int stride = gridDim.x * blockDim.x;
  float4 z = make_float4(0.f, 0.f, 0.f, 0.f);
  for (; i < n4; i += stride) p[i] = z;
}

__global__ __launch_bounds__(256) void relu_f4(float4* __restrict__ p, int n4) {
  int i = blockIdx.x * blockDim.x + threadIdx.x;
  int stride = gridDim.x * blockDim.x;
  for (; i < n4; i += stride) {
    float4 v = p[i];
    v.x = fmaxf(v.x, 0.f);
    v.y = fmaxf(v.y, 0.f);
    v.z = fmaxf(v.z, 0.f);
    v.w = fmaxf(v.w, 0.f);
    p[i] = v;
  }
}

// ---------------- dense transform: pre = x @ W[s]  (fp32, VALU) ----------------
// 128x128 output tile per block, 256 threads, 8x8 micro-tile per thread.

__global__ __launch_bounds__(256) void gemm_xw(const float* __restrict__ x,
                                               const float* __restrict__ W,
                                               float* __restrict__ pre,
                                               int n_nodes) {
  __shared__ float xs[128][33];   // 128 rows x 32 k  (+1 pad)
  __shared__ float wt[32][129];   // 32 k x 128 cols  (+1 pad)

  const int tid = threadIdx.x;
  const int row0 = blockIdx.x * 128;
  const int tcol = tid & 15;      // cols: tcol + 16*j
  const int trow = tid >> 4;      // 0..15 -> rows trow*8 + i

  float acc[8][8];
#pragma unroll
  for (int i = 0; i < 8; ++i)
#pragma unroll
    for (int j = 0; j < 8; ++j) acc[i][j] = 0.f;

#pragma unroll 1
  for (int kk = 0; kk < N_DIN; kk += 32) {
    // stage x tile: 128x32 floats = 1024 float4, 4 per thread
#pragma unroll
    for (int i = 0; i < 4; ++i) {
      int e = tid + i * 256;
      int r = e >> 3, c = (e & 7) * 4;
      int gr = row0 + r;
      float4 v = make_float4(0.f, 0.f, 0.f, 0.f);
      if (gr < n_nodes)
        v = *reinterpret_cast<const float4*>(&x[(size_t)gr * N_DIN + kk + c]);
      xs[r][c] = v.x; xs[r][c + 1] = v.y; xs[r][c + 2] = v.z; xs[r][c + 3] = v.w;
    }
    // stage W tile: 32x128 floats = 1024 float4, 4 per thread
#pragma unroll
    for (int i = 0; i < 4; ++i) {
      int e = tid + i * 256;
      int k = e >> 5, c = (e & 31) * 4;
      float4 v = *reinterpret_cast<const float4*>(&W[(size_t)(kk + k) * N_DOUT + c]);
      wt[k][c] = v.x; wt[k][c + 1] = v.y; wt[k][c + 2] = v.z; wt[k][c + 3] = v.w;
    }
    __syncthreads();

#pragma unroll 4
    for (int k = 0; k < 32; ++k) {
      float a[8], b[8];
#pragma unroll
      for (int i = 0; i < 8; ++i) a[i] = xs[trow * 8 + i][k];
#pragma unroll
      for (int j = 0; j < 8; ++j) b[j] = wt[k][tcol + 16 * j];
#pragma unroll
      for (int i = 0; i < 8; ++i)
#pragma unroll
        for (int j = 0; j < 8; ++j) acc[i][j] = fmaf(a[i], b[j], acc[i][j]);
    }
    __syncthreads();
  }

#pragma unroll
  for (int i = 0; i < 8; ++i) {
    int gr = row0 + trow * 8 + i;
    if (gr < n_nodes) {
#pragma unroll
      for (int j = 0; j < 8; ++j)
        pre[(size_t)gr * N_DOUT + tcol + 16 * j] = acc[i][j];
    }
  }
}

// ---------------- SpMM scatter: out[dst] += val * pre[src]  (atomics) ----------------
// One wave (64 lanes) per edge; each lane handles 2 columns (float2 gather).

__global__ __launch_bounds__(256) void spmm_atomic(const float* __restrict__ pre,
                                                   const int* __restrict__ src,
                                                   const int* __restrict__ dst,
                                                   const float* __restrict__ val,
                                                   float* __restrict__ out,
                                                   int n_edges) {
  const int lane = threadIdx.x & 63;
  const int wave = blockIdx.x * (blockDim.x >> 6) + (threadIdx.x >> 6);
  const int nwaves = gridDim.x * (blockDim.x >> 6);

  for (int e = wave; e < n_edges; e += nwaves) {
    int s = src[e];
    int d = dst[e];
    float v = val[e];
    const float2 p = *reinterpret_cast<const float2*>(&pre[(size_t)s * N_DOUT + lane * 2]);
    float* o = &out[(size_t)d * N_DOUT + lane * 2];
    atomicAdd(o, v * p.x);
    atomicAdd(o + 1, v * p.y);
  }
}

// ---------------- host launch ----------------

extern "C" void kernel_launch(void* const* d_in, const int* in_sizes, int n_in,
                              void* d_out, int out_size, void* d_ws, size_t ws_size,
                              hipStream_t stream) {
  const float* x    = (const float*)d_in[0];
  const float* W    = (const float*)d_in[1];
  const int*   esrc = (const int*)d_in[2];
  const int*   edst = (const int*)d_in[3];
  const float* eval_ = (const float*)d_in[4];
  float* out = (float*)d_out;
  float* pre = (float*)d_ws;

  const int n_nodes    = in_sizes[0] / N_DIN;               // 100000
  const int n_supports = in_sizes[1] / (N_DIN * N_DOUT);    // 3
  const int n_edges    = in_sizes[2] / n_supports;          // 500000

  const size_t need = (size_t)n_nodes * N_DOUT * sizeof(float);
  if (ws_size < need) return;  // workspace too small — signals restructure needed

  const int n4 = out_size / 4;
  zero_f4<<<2048, 256, 0, stream>>>((float4*)out, n4);

  const int gemm_blocks = (n_nodes + 127) / 128;
  for (int s = 0; s < n_supports; ++s) {
    gemm_xw<<<gemm_blocks, 256, 0, stream>>>(
        x, W + (size_t)s * N_DIN * N_DOUT, pre, n_nodes);
    spmm_atomic<<<2048, 256, 0, stream>>>(
        pre, esrc + (size_t)s * n_edges, edst + (size_t)s * n_edges,
        eval_ + (size_t)s * n_edges, out, n_edges);
  }

  relu_f4<<<2048, 256, 0, stream>>>((float4*)out, n4);
}

// Round 2
// 560.218 us; speedup vs baseline: 2.5600x; 2.5600x over previous
//
#include <hip/hip_runtime.h>

#define DIN 128
#define DOUT 128

// ======================= dense transform: pre = x @ W[s] =======================
// 128x128 output tile per block, 256 threads, 8x8 micro-tile per thread (fp32 VALU).

__global__ __launch_bounds__(256) void gemm_xw(const float* __restrict__ x,
                                               const float* __restrict__ W,
                                               float* __restrict__ pre,
                                               int n_nodes) {
  __shared__ float xs[128][33];
  __shared__ float wt[32][129];

  const int tid = threadIdx.x;
  const int row0 = blockIdx.x * 128;
  const int tcol = tid & 15;
  const int trow = tid >> 4;

  float acc[8][8];
#pragma unroll
  for (int i = 0; i < 8; ++i)
#pragma unroll
    for (int j = 0; j < 8; ++j) acc[i][j] = 0.f;

#pragma unroll 1
  for (int kk = 0; kk < DIN; kk += 32) {
#pragma unroll
    for (int i = 0; i < 4; ++i) {
      int e = tid + i * 256;
      int r = e >> 3, c = (e & 7) * 4;
      int gr = row0 + r;
      float4 v = make_float4(0.f, 0.f, 0.f, 0.f);
      if (gr < n_nodes)
        v = *reinterpret_cast<const float4*>(&x[(size_t)gr * DIN + kk + c]);
      xs[r][c] = v.x; xs[r][c + 1] = v.y; xs[r][c + 2] = v.z; xs[r][c + 3] = v.w;
    }
#pragma unroll
    for (int i = 0; i < 4; ++i) {
      int e = tid + i * 256;
      int k = e >> 5, c = (e & 31) * 4;
      float4 v = *reinterpret_cast<const float4*>(&W[(size_t)(kk + k) * DOUT + c]);
      wt[k][c] = v.x; wt[k][c + 1] = v.y; wt[k][c + 2] = v.z; wt[k][c + 3] = v.w;
    }
    __syncthreads();

#pragma unroll 4
    for (int k = 0; k < 32; ++k) {
      float a[8], b[8];
#pragma unroll
      for (int i = 0; i < 8; ++i) a[i] = xs[trow * 8 + i][k];
#pragma unroll
      for (int j = 0; j < 8; ++j) b[j] = wt[k][tcol + 16 * j];
#pragma unroll
      for (int i = 0; i < 8; ++i)
#pragma unroll
        for (int j = 0; j < 8; ++j) acc[i][j] = fmaf(a[i], b[j], acc[i][j]);
    }
    __syncthreads();
  }

#pragma unroll
  for (int i = 0; i < 8; ++i) {
    int gr = row0 + trow * 8 + i;
    if (gr < n_nodes) {
#pragma unroll
      for (int j = 0; j < 8; ++j)
        pre[(size_t)gr * DOUT + tcol + 16 * j] = acc[i][j];
    }
  }
}

// ======================= CSR build (per support) =======================

__global__ __launch_bounds__(256) void zero_i32(int* __restrict__ p, int n) {
  int i = blockIdx.x * blockDim.x + threadIdx.x;
  if (i < n) p[i] = 0;
}

__global__ __launch_bounds__(256) void edge_hist(const int* __restrict__ dst,
                                                 int* __restrict__ counts, int n_edges) {
  int i = blockIdx.x * blockDim.x + threadIdx.x;
  if (i < n_edges) atomicAdd(&counts[dst[i]], 1);
}

// two-level exclusive scan over counts[n] -> row_off[n]; block = 256 thr x 4 elems
__global__ __launch_bounds__(256) void scan_local(const int* __restrict__ counts,
                                                  int* __restrict__ row_off,
                                                  int* __restrict__ partials, int n) {
  __shared__ int tmp[256];
  const int tid = threadIdx.x;
  const int base = blockIdx.x * 1024 + tid * 4;
  int v[4];
#pragma unroll
  for (int i = 0; i < 4; ++i) v[i] = (base + i < n) ? counts[base + i] : 0;
  int s = v[0] + v[1] + v[2] + v[3];
  tmp[tid] = s;
  __syncthreads();
#pragma unroll
  for (int d = 1; d < 256; d <<= 1) {
    int t = (tid >= d) ? tmp[tid - d] : 0;
    __syncthreads();
    tmp[tid] += t;
    __syncthreads();
  }
  int excl = tmp[tid] - s;
  int p = excl;
#pragma unroll
  for (int i = 0; i < 4; ++i) {
    if (base + i < n) row_off[base + i] = p;
    p += v[i];
  }
  if (tid == 255) partials[blockIdx.x] = tmp[255];  // block total
}

__global__ __launch_bounds__(256) void scan_partials_k(int* __restrict__ partials, int nblk) {
  __shared__ int tmp[256];
  const int tid = threadIdx.x;
  int v = (tid < nblk) ? partials[tid] : 0;
  tmp[tid] = v;
  __syncthreads();
#pragma unroll
  for (int d = 1; d < 256; d <<= 1) {
    int t = (tid >= d) ? tmp[tid - d] : 0;
    __syncthreads();
    tmp[tid] += t;
    __syncthreads();
  }
  if (tid < nblk) partials[tid] = tmp[tid] - v;  // exclusive
}

__global__ __launch_bounds__(256) void scan_finish(int* __restrict__ row_off,
                                                   int* __restrict__ cursor,
                                                   const int* __restrict__ partials,
                                                   int n, int n_edges) {
  const int off = partials[blockIdx.x];
  const int base = blockIdx.x * 1024 + threadIdx.x * 4;
#pragma unroll
  for (int i = 0; i < 4; ++i) {
    int idx = base + i;
    if (idx < n) {
      int v = row_off[idx] + off;
      row_off[idx] = v;
      cursor[idx] = v;
    }
  }
  if (blockIdx.x == 0 && threadIdx.x == 0) row_off[n] = n_edges;
}

__global__ __launch_bounds__(256) void edge_fill(const int* __restrict__ src,
                                                 const int* __restrict__ dst,
                                                 const float* __restrict__ val,
                                                 int* __restrict__ cursor,
                                                 int* __restrict__ csr_src,
                                                 float* __restrict__ csr_val, int n_edges) {
  int i = blockIdx.x * blockDim.x + threadIdx.x;
  if (i < n_edges) {
    int d = dst[i];
    int pos = atomicAdd(&cursor[d], 1);
    csr_src[pos] = src[i];
    csr_val[pos] = val[i];
  }
}

// ======================= SpMM gather: one wave per dst node =======================
// mode bit0: accumulate into existing out; bit1: apply relu before store.

__global__ __launch_bounds__(256) void spmm_gather(const float* __restrict__ pre,
                                                   const int* __restrict__ csr_src,
                                                   const float* __restrict__ csr_val,
                                                   const int* __restrict__ row_off,
                                                   float* __restrict__ out,
                                                   int n_nodes, int mode) {
  const int lane = threadIdx.x & 63;
  const int wave = blockIdx.x * (blockDim.x >> 6) + (threadIdx.x >> 6);
  const int nwaves = gridDim.x * (blockDim.x >> 6);

  for (int n = wave; n < n_nodes; n += nwaves) {
    const int beg = row_off[n];
    const int end = row_off[n + 1];
    float ax = 0.f, ay = 0.f;
    for (int j = beg; j < end; ++j) {
      const int s = csr_src[j];
      const float v = csr_val[j];
      const float2 p = *reinterpret_cast<const float2*>(&pre[(size_t)s * DOUT + lane * 2]);
      ax = fmaf(v, p.x, ax);
      ay = fmaf(v, p.y, ay);
    }
    float2* o = reinterpret_cast<float2*>(&out[(size_t)n * DOUT + lane * 2]);
    if (mode & 1) {
      float2 prev = *o;
      ax += prev.x;
      ay += prev.y;
    }
    if (mode & 2) {
      ax = fmaxf(ax, 0.f);
      ay = fmaxf(ay, 0.f);
    }
    *o = make_float2(ax, ay);
  }
}

// ======================= fallback (atomic) path helpers =======================

__global__ __launch_bounds__(256) void zero_f4(float4* __restrict__ p, int n4) {
  int i = blockIdx.x * blockDim.x + threadIdx.x;
  int stride = gridDim.x * blockDim.x;
  float4 z = make_float4(0.f, 0.f, 0.f, 0.f);
  for (; i < n4; i += stride) p[i] = z;
}

__global__ __launch_bounds__(256) void relu_f4(float4* __restrict__ p, int n4) {
  int i = blockIdx.x * blockDim.x + threadIdx.x;
  int stride = gridDim.x * blockDim.x;
  for (; i < n4; i += stride) {
    float4 v = p[i];
    v.x = fmaxf(v.x, 0.f); v.y = fmaxf(v.y, 0.f);
    v.z = fmaxf(v.z, 0.f); v.w = fmaxf(v.w, 0.f);
    p[i] = v;
  }
}

__global__ __launch_bounds__(256) void spmm_atomic(const float* __restrict__ pre,
                                                   const int* __restrict__ src,
                                                   const int* __restrict__ dst,
                                                   const float* __restrict__ val,
                                                   float* __restrict__ out,
                                                   int n_edges) {
  const int lane = threadIdx.x & 63;
  const int wave = blockIdx.x * (blockDim.x >> 6) + (threadIdx.x >> 6);
  const int nwaves = gridDim.x * (blockDim.x >> 6);
  for (int e = wave; e < n_edges; e += nwaves) {
    int s = src[e];
    int d = dst[e];
    float v = val[e];
    const float2 p = *reinterpret_cast<const float2*>(&pre[(size_t)s * DOUT + lane * 2]);
    float* o = &out[(size_t)d * DOUT + lane * 2];
    atomicAdd(o, v * p.x);
    atomicAdd(o + 1, v * p.y);
  }
}

// ======================= host launch =======================

static inline size_t align_up(size_t v, size_t a) { return (v + a - 1) & ~(a - 1); }

extern "C" void kernel_launch(void* const* d_in, const int* in_sizes, int n_in,
                              void* d_out, int out_size, void* d_ws, size_t ws_size,
                              hipStream_t stream) {
  const float* x     = (const float*)d_in[0];
  const float* W     = (const float*)d_in[1];
  const int*   esrc  = (const int*)d_in[2];
  const int*   edst  = (const int*)d_in[3];
  const float* eval_ = (const float*)d_in[4];
  float* out = (float*)d_out;

  const int n_nodes    = in_sizes[0] / DIN;              // 100000
  const int n_supports = in_sizes[1] / (DIN * DOUT);     // 3
  const int n_edges    = in_sizes[2] / n_supports;       // 500000

  // workspace layout
  char* w = (char*)d_ws;
  size_t off = 0;
  float* pre = (float*)(w + off);     off += align_up((size_t)n_nodes * DOUT * 4, 256);
  int* row_off = (int*)(w + off);     off += align_up((size_t)(n_nodes + 1) * 4, 256);
  int* cursor = (int*)(w + off);      off += align_up((size_t)n_nodes * 4, 256);
  int* csr_src = (int*)(w + off);     off += align_up((size_t)n_edges * 4, 256);
  float* csr_val = (float*)(w + off); off += align_up((size_t)n_edges * 4, 256);
  int* partials = (int*)(w + off);    off += align_up(1024 * 4, 256);

  const int gemm_blocks = (n_nodes + 127) / 128;
  const int node_blocks = (n_nodes + 255) / 256;
  const int edge_blocks = (n_edges + 255) / 256;
  const int scan_blocks = (n_nodes + 1023) / 1024;   // 98 for 100k (must be <= 256)
  const int gather_blocks = (n_nodes + 3) / 4;       // 4 waves per 256-thr block

  if (off > ws_size || scan_blocks > 256) {
    // fallback: atomic scatter path (only needs pre)
    if (ws_size < (size_t)n_nodes * DOUT * 4) return;
    const int n4 = out_size / 4;
    zero_f4<<<2048, 256, 0, stream>>>((float4*)out, n4);
    for (int s = 0; s < n_supports; ++s) {
      gemm_xw<<<gemm_blocks, 256, 0, stream>>>(x, W + (size_t)s * DIN * DOUT, pre, n_nodes);
      spmm_atomic<<<2048, 256, 0, stream>>>(pre, esrc + (size_t)s * n_edges,
                                            edst + (size_t)s * n_edges,
                                            eval_ + (size_t)s * n_edges, out, n_edges);
    }
    relu_f4<<<2048, 256, 0, stream>>>((float4*)out, n4);
    return;
  }

  for (int s = 0; s < n_supports; ++s) {
    const int* src = esrc + (size_t)s * n_edges;
    const int* dst = edst + (size_t)s * n_edges;
    const float* val = eval_ + (size_t)s * n_edges;

    gemm_xw<<<gemm_blocks, 256, 0, stream>>>(x, W + (size_t)s * DIN * DOUT, pre, n_nodes);

    // CSR build keyed by destination (cursor doubles as the counts buffer)
    zero_i32<<<node_blocks, 256, 0, stream>>>(cursor, n_nodes);
    edge_hist<<<edge_blocks, 256, 0, stream>>>(dst, cursor, n_edges);
    scan_local<<<scan_blocks, 256, 0, stream>>>(cursor, row_off, partials, n_nodes);
    scan_partials_k<<<1, 256, 0, stream>>>(partials, scan_blocks);
    scan_finish<<<scan_blocks, 256, 0, stream>>>(row_off, cursor, partials, n_nodes, n_edges);
    edge_fill<<<edge_blocks, 256, 0, stream>>>(src, dst, val, cursor, csr_src, csr_val, n_edges);

    // gather: s==0 -> overwrite; middle -> accumulate; last -> accumulate + relu
    int mode = (s == 0) ? 0 : 1;
    if (s == n_supports - 1) mode |= 2;
    spmm_gather<<<gather_blocks, 256, 0, stream>>>(pre, csr_src, csr_val, row_off, out,
                                                   n_nodes, mode);
  }
}

// Round 3
// 479.405 us; speedup vs baseline: 2.9915x; 1.1686x over previous
//
#include <hip/hip_runtime.h>

#define DIN 128
#define DOUT 128

// ======================= dense transform: pre[s] = x @ W[s] =======================
// 128x128 output tile per block, 256 threads, 8x8 micro-tile (fp32 VALU).
// blockIdx.y = support index.

__global__ __launch_bounds__(256) void gemm_xw(const float* __restrict__ x,
                                               const float* __restrict__ W,
                                               float* __restrict__ pre,
                                               int n_nodes) {
  __shared__ float xs[128][33];
  __shared__ float wt[32][129];

  const float* Ws = W + (size_t)blockIdx.y * DIN * DOUT;
  float* pres = pre + (size_t)blockIdx.y * n_nodes * DOUT;

  const int tid = threadIdx.x;
  const int row0 = blockIdx.x * 128;
  const int tcol = tid & 15;
  const int trow = tid >> 4;

  float acc[8][8];
#pragma unroll
  for (int i = 0; i < 8; ++i)
#pragma unroll
    for (int j = 0; j < 8; ++j) acc[i][j] = 0.f;

#pragma unroll 1
  for (int kk = 0; kk < DIN; kk += 32) {
#pragma unroll
    for (int i = 0; i < 4; ++i) {
      int e = tid + i * 256;
      int r = e >> 3, c = (e & 7) * 4;
      int gr = row0 + r;
      float4 v = make_float4(0.f, 0.f, 0.f, 0.f);
      if (gr < n_nodes)
        v = *reinterpret_cast<const float4*>(&x[(size_t)gr * DIN + kk + c]);
      xs[r][c] = v.x; xs[r][c + 1] = v.y; xs[r][c + 2] = v.z; xs[r][c + 3] = v.w;
    }
#pragma unroll
    for (int i = 0; i < 4; ++i) {
      int e = tid + i * 256;
      int k = e >> 5, c = (e & 31) * 4;
      float4 v = *reinterpret_cast<const float4*>(&Ws[(size_t)(kk + k) * DOUT + c]);
      wt[k][c] = v.x; wt[k][c + 1] = v.y; wt[k][c + 2] = v.z; wt[k][c + 3] = v.w;
    }
    __syncthreads();

#pragma unroll 4
    for (int k = 0; k < 32; ++k) {
      float a[8], b[8];
#pragma unroll
      for (int i = 0; i < 8; ++i) a[i] = xs[trow * 8 + i][k];
#pragma unroll
      for (int j = 0; j < 8; ++j) b[j] = wt[k][tcol + 16 * j];
#pragma unroll
      for (int i = 0; i < 8; ++i)
#pragma unroll
        for (int j = 0; j < 8; ++j) acc[i][j] = fmaf(a[i], b[j], acc[i][j]);
    }
    __syncthreads();
  }

#pragma unroll
  for (int i = 0; i < 8; ++i) {
    int gr = row0 + trow * 8 + i;
    if (gr < n_nodes) {
#pragma unroll
      for (int j = 0; j < 8; ++j)
        pres[(size_t)gr * DOUT + tcol + 16 * j] = acc[i][j];
    }
  }
}

// ======================= CSR build (rows = s*n_nodes + dst) =======================

__global__ __launch_bounds__(256) void zero_i32(int* __restrict__ p, int n) {
  int i = blockIdx.x * blockDim.x + threadIdx.x;
  if (i < n) p[i] = 0;
}

// blockIdx.y = support; dst_base points at edge_dst[0] of support 0 of this launch.
__global__ __launch_bounds__(256) void edge_hist(const int* __restrict__ dst_base,
                                                 int* __restrict__ counts,
                                                 int n_edges, int n_nodes) {
  int i = blockIdx.x * blockDim.x + threadIdx.x;
  int s = blockIdx.y;
  if (i < n_edges) atomicAdd(&counts[s * n_nodes + dst_base[(size_t)s * n_edges + i]], 1);
}

// two-level exclusive scan; block covers 2048 elems (256 thr x 8)
__global__ __launch_bounds__(256) void scan_local(const int* __restrict__ counts,
                                                  int* __restrict__ row_off,
                                                  int* __restrict__ partials, int n) {
  __shared__ int tmp[256];
  const int tid = threadIdx.x;
  const int base = blockIdx.x * 2048 + tid * 8;
  int v[8];
#pragma unroll
  for (int i = 0; i < 8; ++i) v[i] = (base + i < n) ? counts[base + i] : 0;
  int s = 0;
#pragma unroll
  for (int i = 0; i < 8; ++i) s += v[i];
  tmp[tid] = s;
  __syncthreads();
#pragma unroll
  for (int d = 1; d < 256; d <<= 1) {
    int t = (tid >= d) ? tmp[tid - d] : 0;
    __syncthreads();
    tmp[tid] += t;
    __syncthreads();
  }
  int p = tmp[tid] - s;  // exclusive prefix of this thread's chunk
#pragma unroll
  for (int i = 0; i < 8; ++i) {
    if (base + i < n) row_off[base + i] = p;
    p += v[i];
  }
  if (tid == 255) partials[blockIdx.x] = tmp[255];
}

__global__ __launch_bounds__(256) void scan_partials_k(int* __restrict__ partials, int nblk) {
  __shared__ int tmp[256];
  const int tid = threadIdx.x;
  int v = (tid < nblk) ? partials[tid] : 0;
  tmp[tid] = v;
  __syncthreads();
#pragma unroll
  for (int d = 1; d < 256; d <<= 1) {
    int t = (tid >= d) ? tmp[tid - d] : 0;
    __syncthreads();
    tmp[tid] += t;
    __syncthreads();
  }
  if (tid < nblk) partials[tid] = tmp[tid] - v;
}

__global__ __launch_bounds__(256) void scan_finish(int* __restrict__ row_off,
                                                   int* __restrict__ cursor,
                                                   const int* __restrict__ partials,
                                                   int n, int total_edges) {
  const int off = partials[blockIdx.x];
  const int base = blockIdx.x * 2048 + threadIdx.x * 8;
#pragma unroll
  for (int i = 0; i < 8; ++i) {
    int idx = base + i;
    if (idx < n) {
      int v = row_off[idx] + off;
      row_off[idx] = v;
      cursor[idx] = v;
    }
  }
  if (blockIdx.x == 0 && threadIdx.x == 0) row_off[n] = total_edges;
}

// blockIdx.y = support
__global__ __launch_bounds__(256) void edge_fill(const int* __restrict__ src_base,
                                                 const int* __restrict__ dst_base,
                                                 const float* __restrict__ val_base,
                                                 int* __restrict__ cursor,
                                                 int2* __restrict__ csr,
                                                 int n_edges, int n_nodes) {
  int i = blockIdx.x * blockDim.x + threadIdx.x;
  int s = blockIdx.y;
  if (i < n_edges) {
    size_t gi = (size_t)s * n_edges + i;
    int d = dst_base[gi];
    int pos = atomicAdd(&cursor[s * n_nodes + d], 1);
    csr[pos] = make_int2(src_base[gi], __float_as_int(val_base[gi]));
  }
}

// ======================= SpMM gather: one wave per dst node =======================
// Sums over n_sup supports; mode bit0: accumulate from out; bit1: relu.

__global__ __launch_bounds__(256) void spmm_gather(const float* __restrict__ pre,
                                                   const int2* __restrict__ csr,
                                                   const int* __restrict__ row_off,
                                                   float* __restrict__ out,
                                                   int n_nodes, int n_sup, int mode) {
  const int lane = threadIdx.x & 63;
  const int wave = blockIdx.x * (blockDim.x >> 6) + (threadIdx.x >> 6);
  const int nwaves = gridDim.x * (blockDim.x >> 6);

  for (int n = wave; n < n_nodes; n += nwaves) {
    float ax = 0.f, ay = 0.f;
    float2* o = reinterpret_cast<float2*>(&out[(size_t)n * DOUT + lane * 2]);
    if (mode & 1) {
      float2 prev = *o;
      ax = prev.x; ay = prev.y;
    }
    for (int s = 0; s < n_sup; ++s) {
      const float* ps = pre + (size_t)s * n_nodes * DOUT;
      const int row = s * n_nodes + n;
      const int beg = row_off[row];
      const int end = row_off[row + 1];
      for (int j = beg; j < end; ++j) {
        const int2 e = csr[j];
        const float v = __int_as_float(e.y);
        const float2 p = *reinterpret_cast<const float2*>(&ps[(size_t)e.x * DOUT + lane * 2]);
        ax = fmaf(v, p.x, ax);
        ay = fmaf(v, p.y, ay);
      }
    }
    if (mode & 2) {
      ax = fmaxf(ax, 0.f);
      ay = fmaxf(ay, 0.f);
    }
    *o = make_float2(ax, ay);
  }
}

// ======================= atomic fallback helpers =======================

__global__ __launch_bounds__(256) void zero_f4(float4* __restrict__ p, int n4) {
  int i = blockIdx.x * blockDim.x + threadIdx.x;
  int stride = gridDim.x * blockDim.x;
  float4 z = make_float4(0.f, 0.f, 0.f, 0.f);
  for (; i < n4; i += stride) p[i] = z;
}

__global__ __launch_bounds__(256) void relu_f4(float4* __restrict__ p, int n4) {
  int i = blockIdx.x * blockDim.x + threadIdx.x;
  int stride = gridDim.x * blockDim.x;
  for (; i < n4; i += stride) {
    float4 v = p[i];
    v.x = fmaxf(v.x, 0.f); v.y = fmaxf(v.y, 0.f);
    v.z = fmaxf(v.z, 0.f); v.w = fmaxf(v.w, 0.f);
    p[i] = v;
  }
}

__global__ __launch_bounds__(256) void spmm_atomic(const float* __restrict__ pre,
                                                   const int* __restrict__ src,
                                                   const int* __restrict__ dst,
                                                   const float* __restrict__ val,
                                                   float* __restrict__ out,
                                                   int n_edges) {
  const int lane = threadIdx.x & 63;
  const int wave = blockIdx.x * (blockDim.x >> 6) + (threadIdx.x >> 6);
  const int nwaves = gridDim.x * (blockDim.x >> 6);
  for (int e = wave; e < n_edges; e += nwaves) {
    int s = src[e];
    int d = dst[e];
    float v = val[e];
    const float2 p = *reinterpret_cast<const float2*>(&pre[(size_t)s * DOUT + lane * 2]);
    float* o = &out[(size_t)d * DOUT + lane * 2];
    atomicAdd(o, v * p.x);
    atomicAdd(o + 1, v * p.y);
  }
}

// ======================= host launch =======================

static inline size_t align_up(size_t v, size_t a) { return (v + a - 1) & ~(a - 1); }

extern "C" void kernel_launch(void* const* d_in, const int* in_sizes, int n_in,
                              void* d_out, int out_size, void* d_ws, size_t ws_size,
                              hipStream_t stream) {
  const float* x     = (const float*)d_in[0];
  const float* W     = (const float*)d_in[1];
  const int*   esrc  = (const int*)d_in[2];
  const int*   edst  = (const int*)d_in[3];
  const float* eval_ = (const float*)d_in[4];
  float* out = (float*)d_out;

  const int n_nodes    = in_sizes[0] / DIN;              // 100000
  const int n_supports = in_sizes[1] / (DIN * DOUT);     // 3
  const int n_edges    = in_sizes[2] / n_supports;       // 500000

  const int gemm_blocks = (n_nodes + 127) / 128;
  const int edge_blocks = (n_edges + 255) / 256;
  const int gather_blocks = (n_nodes + 3) / 4;

  // -------- tier 1: merged (all supports in one CSR + one gather) --------
  {
    const int NR = n_supports * n_nodes;             // total CSR rows
    const int TE = n_supports * n_edges;             // total CSR edges
    const int scan_blocks = (NR + 2047) / 2048;
    char* w = (char*)d_ws;
    size_t off = 0;
    float* pre3 = (float*)(w + off);   off += align_up((size_t)NR * DOUT * 4, 256);
    int* row_off = (int*)(w + off);    off += align_up((size_t)(NR + 1) * 4, 256);
    int* cursor = (int*)(w + off);     off += align_up((size_t)NR * 4, 256);
    int2* csr = (int2*)(w + off);      off += align_up((size_t)TE * 8, 256);
    int* partials = (int*)(w + off);   off += align_up(1024 * 4, 256);

    if (off <= ws_size && scan_blocks <= 256) {
      gemm_xw<<<dim3(gemm_blocks, n_supports), 256, 0, stream>>>(x, W, pre3, n_nodes);
      zero_i32<<<(NR + 255) / 256, 256, 0, stream>>>(cursor, NR);
      edge_hist<<<dim3(edge_blocks, n_supports), 256, 0, stream>>>(edst, cursor, n_edges, n_nodes);
      scan_local<<<scan_blocks, 256, 0, stream>>>(cursor, row_off, partials, NR);
      scan_partials_k<<<1, 256, 0, stream>>>(partials, scan_blocks);
      scan_finish<<<scan_blocks, 256, 0, stream>>>(row_off, cursor, partials, NR, TE);
      edge_fill<<<dim3(edge_blocks, n_supports), 256, 0, stream>>>(esrc, edst, eval_, cursor,
                                                                   csr, n_edges, n_nodes);
      spmm_gather<<<gather_blocks, 256, 0, stream>>>(pre3, csr, row_off, out,
                                                     n_nodes, n_supports, /*relu*/ 2);
      return;
    }
  }

  // -------- tier 2: per-support CSR gather --------
  {
    const int scan_blocks = (n_nodes + 2047) / 2048;
    char* w = (char*)d_ws;
    size_t off = 0;
    float* pre = (float*)(w + off);    off += align_up((size_t)n_nodes * DOUT * 4, 256);
    int* row_off = (int*)(w + off);    off += align_up((size_t)(n_nodes + 1) * 4, 256);
    int* cursor = (int*)(w + off);     off += align_up((size_t)n_nodes * 4, 256);
    int2* csr = (int2*)(w + off);      off += align_up((size_t)n_edges * 8, 256);
    int* partials = (int*)(w + off);   off += align_up(1024 * 4, 256);

    if (off <= ws_size && scan_blocks <= 256) {
      for (int s = 0; s < n_supports; ++s) {
        const int* src = esrc + (size_t)s * n_edges;
        const int* dst = edst + (size_t)s * n_edges;
        const float* val = eval_ + (size_t)s * n_edges;
        gemm_xw<<<dim3(gemm_blocks, 1), 256, 0, stream>>>(x, W + (size_t)s * DIN * DOUT,
                                                          pre, n_nodes);
        zero_i32<<<(n_nodes + 255) / 256, 256, 0, stream>>>(cursor, n_nodes);
        edge_hist<<<dim3(edge_blocks, 1), 256, 0, stream>>>(dst, cursor, n_edges, n_nodes);
        scan_local<<<scan_blocks, 256, 0, stream>>>(cursor, row_off, partials, n_nodes);
        scan_partials_k<<<1, 256, 0, stream>>>(partials, scan_blocks);
        scan_finish<<<scan_blocks, 256, 0, stream>>>(row_off, cursor, partials, n_nodes, n_edges);
        edge_fill<<<dim3(edge_blocks, 1), 256, 0, stream>>>(src, dst, val, cursor, csr,
                                                            n_edges, n_nodes);
        int mode = (s == 0) ? 0 : 1;
        if (s == n_supports - 1) mode |= 2;
        spmm_gather<<<gather_blocks, 256, 0, stream>>>(pre, csr, row_off, out,
                                                       n_nodes, 1, mode);
      }
      return;
    }
  }

  // -------- tier 3: atomic scatter --------
  {
    float* pre = (float*)d_ws;
    if (ws_size < (size_t)n_nodes * DOUT * 4) return;
    const int n4 = out_size / 4;
    zero_f4<<<2048, 256, 0, stream>>>((float4*)out, n4);
    for (int s = 0; s < n_supports; ++s) {
      gemm_xw<<<dim3(gemm_blocks, 1), 256, 0, stream>>>(x, W + (size_t)s * DIN * DOUT,
                                                        pre, n_nodes);
      spmm_atomic<<<2048, 256, 0, stream>>>(pre, esrc + (size_t)s * n_edges,
                                            edst + (size_t)s * n_edges,
                                            eval_ + (size_t)s * n_edges, out, n_edges);
    }
    relu_f4<<<2048, 256, 0, stream>>>((float4*)out, n4);
  }
}

// Round 4
// 412.762 us; speedup vs baseline: 3.4745x; 1.1615x over previous
//
#include <hip/hip_runtime.h>

#define DIN 128
#define DOUT 128

typedef __attribute__((ext_vector_type(8))) short short8;
typedef __attribute__((ext_vector_type(4))) float f32x4;
typedef __attribute__((ext_vector_type(8))) unsigned short ushort8;

__device__ __forceinline__ unsigned short f2bf(float f) {
  unsigned int u = __float_as_uint(f);
  u += 0x7fffu + ((u >> 16) & 1u);   // round-to-nearest-even
  return (unsigned short)(u >> 16);
}

// ======================= MFMA GEMM: pre[s] = bf16(x @ W[s]) =======================
// One block = 128-row tile, loops all supports internally. 256 thr = 4 waves.
// Wave w owns rows [w*32, w*32+32): 2 m-tiles x 8 n-tiles of 16x16, K = 4 chunks of 32.

__global__ __launch_bounds__(256) void gemm_mfma(const float* __restrict__ x,
                                                 const float* __restrict__ W,
                                                 unsigned short* __restrict__ pre,
                                                 int n_nodes, int n_sup) {
  __shared__ unsigned short xs[128][136];  // x tile bf16, padded (272B row, 16B aligned)
  __shared__ unsigned short wt[128][136];  // W^T bf16 [n][k]; reused as C-stage

  const int tid = threadIdx.x;
  const int lane = tid & 63;
  const int w = tid >> 6;
  const int row0 = blockIdx.x * 128;
  const int alr = lane & 15;   // row (A) / col (B) / col (C)
  const int akg = lane >> 4;   // k-group of 8 (A,B) / row-group of 4 (C)

  // ---- stage x tile (fp32 -> bf16), 4096 float4 / 256 thr = 16 each ----
#pragma unroll
  for (int i = 0; i < 16; ++i) {
    int e = tid + i * 256;
    int r = e >> 5;
    int c = (e & 31) * 4;
    int gr = row0 + r;
    float4 v = make_float4(0.f, 0.f, 0.f, 0.f);
    if (gr < n_nodes) v = *reinterpret_cast<const float4*>(&x[(size_t)gr * DIN + c]);
    xs[r][c] = f2bf(v.x); xs[r][c + 1] = f2bf(v.y);
    xs[r][c + 2] = f2bf(v.z); xs[r][c + 3] = f2bf(v.w);
  }
  __syncthreads();

  // ---- hoist A fragments for all 4 k-chunks, 2 m-tiles ----
  short8 afrag[4][2];
#pragma unroll
  for (int kc = 0; kc < 4; ++kc)
#pragma unroll
    for (int mt = 0; mt < 2; ++mt)
      afrag[kc][mt] = *reinterpret_cast<const short8*>(
          &xs[w * 32 + mt * 16 + alr][kc * 32 + akg * 8]);

  for (int s = 0; s < n_sup; ++s) {
    const float* Ws = W + (size_t)s * DIN * DOUT;
    __syncthreads();  // protect wt from previous iteration's store-stage readers
    // ---- stage W^T (fp32 [k][n] -> bf16 wt[n][k]) ----
#pragma unroll
    for (int i = 0; i < 16; ++i) {
      int e = tid + i * 256;
      int k = e >> 5;
      int c = (e & 31) * 4;
      float4 v = *reinterpret_cast<const float4*>(&Ws[(size_t)k * DOUT + c]);
      wt[c][k] = f2bf(v.x); wt[c + 1][k] = f2bf(v.y);
      wt[c + 2][k] = f2bf(v.z); wt[c + 3][k] = f2bf(v.w);
    }
    __syncthreads();

    f32x4 acc[2][8];
#pragma unroll
    for (int mt = 0; mt < 2; ++mt)
#pragma unroll
      for (int nt = 0; nt < 8; ++nt) acc[mt][nt] = (f32x4){0.f, 0.f, 0.f, 0.f};

#pragma unroll
    for (int kc = 0; kc < 4; ++kc) {
      short8 bfrag[8];
#pragma unroll
      for (int nt = 0; nt < 8; ++nt)
        bfrag[nt] = *reinterpret_cast<const short8*>(
            &wt[nt * 16 + alr][kc * 32 + akg * 8]);
#pragma unroll
      for (int mt = 0; mt < 2; ++mt)
#pragma unroll
        for (int nt = 0; nt < 8; ++nt)
          acc[mt][nt] = __builtin_amdgcn_mfma_f32_16x16x32_bf16(
              afrag[kc][mt], bfrag[nt], acc[mt][nt], 0, 0, 0);
    }
    __syncthreads();

    // ---- C-stage into wt as bf16: row = w*32+mt*16+akg*4+q, col = nt*16+alr ----
#pragma unroll
    for (int mt = 0; mt < 2; ++mt)
#pragma unroll
      for (int nt = 0; nt < 8; ++nt)
#pragma unroll
        for (int q = 0; q < 4; ++q)
          wt[w * 32 + mt * 16 + akg * 4 + q][nt * 16 + alr] = f2bf(acc[mt][nt][q]);
    __syncthreads();

    // ---- coalesced store: 2048 ushort8 chunks / 256 thr = 8 each ----
    unsigned short* ps = pre + (size_t)s * n_nodes * DOUT;
#pragma unroll
    for (int i = 0; i < 8; ++i) {
      int e = tid + i * 256;
      int r = e >> 4;
      int c = (e & 15) * 8;
      int gr = row0 + r;
      if (gr < n_nodes)
        *reinterpret_cast<ushort8*>(&ps[(size_t)gr * DOUT + c]) =
            *reinterpret_cast<const ushort8*>(&wt[r][c]);
    }
  }
}

// ======================= fp32 fallback GEMM (tiers 2/3) =======================

__global__ __launch_bounds__(256) void gemm_xw(const float* __restrict__ x,
                                               const float* __restrict__ W,
                                               float* __restrict__ pre,
                                               int n_nodes) {
  __shared__ float xsf[128][33];
  __shared__ float wtf[32][129];
  const float* Ws = W + (size_t)blockIdx.y * DIN * DOUT;
  float* pres = pre + (size_t)blockIdx.y * n_nodes * DOUT;
  const int tid = threadIdx.x;
  const int row0 = blockIdx.x * 128;
  const int tcol = tid & 15;
  const int trow = tid >> 4;
  float acc[8][8];
#pragma unroll
  for (int i = 0; i < 8; ++i)
#pragma unroll
    for (int j = 0; j < 8; ++j) acc[i][j] = 0.f;
#pragma unroll 1
  for (int kk = 0; kk < DIN; kk += 32) {
#pragma unroll
    for (int i = 0; i < 4; ++i) {
      int e = tid + i * 256;
      int r = e >> 3, c = (e & 7) * 4;
      int gr = row0 + r;
      float4 v = make_float4(0.f, 0.f, 0.f, 0.f);
      if (gr < n_nodes)
        v = *reinterpret_cast<const float4*>(&x[(size_t)gr * DIN + kk + c]);
      xsf[r][c] = v.x; xsf[r][c + 1] = v.y; xsf[r][c + 2] = v.z; xsf[r][c + 3] = v.w;
    }
#pragma unroll
    for (int i = 0; i < 4; ++i) {
      int e = tid + i * 256;
      int k = e >> 5, c = (e & 31) * 4;
      float4 v = *reinterpret_cast<const float4*>(&Ws[(size_t)(kk + k) * DOUT + c]);
      wtf[k][c] = v.x; wtf[k][c + 1] = v.y; wtf[k][c + 2] = v.z; wtf[k][c + 3] = v.w;
    }
    __syncthreads();
#pragma unroll 4
    for (int k = 0; k < 32; ++k) {
      float a[8], b[8];
#pragma unroll
      for (int i = 0; i < 8; ++i) a[i] = xsf[trow * 8 + i][k];
#pragma unroll
      for (int j = 0; j < 8; ++j) b[j] = wtf[k][tcol + 16 * j];
#pragma unroll
      for (int i = 0; i < 8; ++i)
#pragma unroll
        for (int j = 0; j < 8; ++j) acc[i][j] = fmaf(a[i], b[j], acc[i][j]);
    }
    __syncthreads();
  }
#pragma unroll
  for (int i = 0; i < 8; ++i) {
    int gr = row0 + trow * 8 + i;
    if (gr < n_nodes) {
#pragma unroll
      for (int j = 0; j < 8; ++j)
        pres[(size_t)gr * DOUT + tcol + 16 * j] = acc[i][j];
    }
  }
}

// ======================= CSR build (rows = s*n_nodes + dst) =======================

__global__ __launch_bounds__(256) void edge_hist(const int* __restrict__ dst_base,
                                                 int* __restrict__ counts,
                                                 int n_edges, int n_nodes) {
  int i = blockIdx.x * blockDim.x + threadIdx.x;
  int s = blockIdx.y;
  if (i < n_edges) atomicAdd(&counts[s * n_nodes + dst_base[(size_t)s * n_edges + i]], 1);
}

__global__ __launch_bounds__(256) void scan_local(const int* __restrict__ counts,
                                                  int* __restrict__ row_off,
                                                  int* __restrict__ partials, int n) {
  __shared__ int tmp[256];
  const int tid = threadIdx.x;
  const int base = blockIdx.x * 2048 + tid * 8;
  int v[8];
#pragma unroll
  for (int i = 0; i < 8; ++i) v[i] = (base + i < n) ? counts[base + i] : 0;
  int s = 0;
#pragma unroll
  for (int i = 0; i < 8; ++i) s += v[i];
  tmp[tid] = s;
  __syncthreads();
#pragma unroll
  for (int d = 1; d < 256; d <<= 1) {
    int t = (tid >= d) ? tmp[tid - d] : 0;
    __syncthreads();
    tmp[tid] += t;
    __syncthreads();
  }
  int p = tmp[tid] - s;
#pragma unroll
  for (int i = 0; i < 8; ++i) {
    if (base + i < n) row_off[base + i] = p;
    p += v[i];
  }
  if (tid == 255) partials[blockIdx.x] = tmp[255];
}

__global__ __launch_bounds__(256) void scan_partials_k(int* __restrict__ partials, int nblk) {
  __shared__ int tmp[256];
  const int tid = threadIdx.x;
  int v = (tid < nblk) ? partials[tid] : 0;
  tmp[tid] = v;
  __syncthreads();
#pragma unroll
  for (int d = 1; d < 256; d <<= 1) {
    int t = (tid >= d) ? tmp[tid - d] : 0;
    __syncthreads();
    tmp[tid] += t;
    __syncthreads();
  }
  if (tid < nblk) partials[tid] = tmp[tid] - v;
}

__global__ __launch_bounds__(256) void scan_finish(int* __restrict__ row_off,
                                                   int* __restrict__ cursor,
                                                   const int* __restrict__ partials,
                                                   int n, int total_edges) {
  const int off = partials[blockIdx.x];
  const int base = blockIdx.x * 2048 + threadIdx.x * 8;
#pragma unroll
  for (int i = 0; i < 8; ++i) {
    int idx = base + i;
    if (idx < n) {
      int v = row_off[idx] + off;
      row_off[idx] = v;
      cursor[idx] = v;
    }
  }
  if (blockIdx.x == 0 && threadIdx.x == 0) row_off[n] = total_edges;
}

__global__ __launch_bounds__(256) void edge_fill(const int* __restrict__ src_base,
                                                 const int* __restrict__ dst_base,
                                                 const float* __restrict__ val_base,
                                                 int* __restrict__ cursor,
                                                 int2* __restrict__ csr,
                                                 int n_edges, int n_nodes) {
  int i = blockIdx.x * blockDim.x + threadIdx.x;
  int s = blockIdx.y;
  if (i < n_edges) {
    size_t gi = (size_t)s * n_edges + i;
    int d = dst_base[gi];
    int pos = atomicAdd(&cursor[s * n_nodes + d], 1);
    csr[pos] = make_int2(src_base[gi], __float_as_int(val_base[gi]));
  }
}

// ======================= gather (bf16 pre): one wave per dst node =======================

__global__ __launch_bounds__(256) void spmm_gather_bf16(const unsigned short* __restrict__ pre,
                                                        const int2* __restrict__ csr,
                                                        const int* __restrict__ row_off,
                                                        float* __restrict__ out,
                                                        int n_nodes, int n_sup) {
  const int lane = threadIdx.x & 63;
  const int wave = blockIdx.x * (blockDim.x >> 6) + (threadIdx.x >> 6);
  const int nwaves = gridDim.x * (blockDim.x >> 6);

  for (int n = wave; n < n_nodes; n += nwaves) {
    float ax = 0.f, ay = 0.f;
    for (int s = 0; s < n_sup; ++s) {
      const unsigned short* ps = pre + (size_t)s * n_nodes * DOUT;
      const int row = s * n_nodes + n;
      const int beg = row_off[row];
      const int end = row_off[row + 1];
      for (int j = beg; j < end; ++j) {
        const int2 e = csr[j];
        const float v = __int_as_float(e.y);
        const unsigned int p =
            *reinterpret_cast<const unsigned int*>(&ps[(size_t)e.x * DOUT + lane * 2]);
        ax = fmaf(v, __uint_as_float(p << 16), ax);
        ay = fmaf(v, __uint_as_float(p & 0xffff0000u), ay);
      }
    }
    ax = fmaxf(ax, 0.f);
    ay = fmaxf(ay, 0.f);
    *reinterpret_cast<float2*>(&out[(size_t)n * DOUT + lane * 2]) = make_float2(ax, ay);
  }
}

// fp32-pre gather for tier 2
__global__ __launch_bounds__(256) void spmm_gather(const float* __restrict__ pre,
                                                   const int2* __restrict__ csr,
                                                   const int* __restrict__ row_off,
                                                   float* __restrict__ out,
                                                   int n_nodes, int n_sup, int mode) {
  const int lane = threadIdx.x & 63;
  const int wave = blockIdx.x * (blockDim.x >> 6) + (threadIdx.x >> 6);
  const int nwaves = gridDim.x * (blockDim.x >> 6);
  for (int n = wave; n < n_nodes; n += nwaves) {
    float ax = 0.f, ay = 0.f;
    float2* o = reinterpret_cast<float2*>(&out[(size_t)n * DOUT + lane * 2]);
    if (mode & 1) { float2 prev = *o; ax = prev.x; ay = prev.y; }
    for (int s = 0; s < n_sup; ++s) {
      const float* ps = pre + (size_t)s * n_nodes * DOUT;
      const int row = s * n_nodes + n;
      const int beg = row_off[row];
      const int end = row_off[row + 1];
      for (int j = beg; j < end; ++j) {
        const int2 e = csr[j];
        const float v = __int_as_float(e.y);
        const float2 p = *reinterpret_cast<const float2*>(&ps[(size_t)e.x * DOUT + lane * 2]);
        ax = fmaf(v, p.x, ax);
        ay = fmaf(v, p.y, ay);
      }
    }
    if (mode & 2) { ax = fmaxf(ax, 0.f); ay = fmaxf(ay, 0.f); }
    *o = make_float2(ax, ay);
  }
}

// ======================= atomic fallback helpers =======================

__global__ __launch_bounds__(256) void zero_f4(float4* __restrict__ p, int n4) {
  int i = blockIdx.x * blockDim.x + threadIdx.x;
  int stride = gridDim.x * blockDim.x;
  float4 z = make_float4(0.f, 0.f, 0.f, 0.f);
  for (; i < n4; i += stride) p[i] = z;
}

__global__ __launch_bounds__(256) void relu_f4(float4* __restrict__ p, int n4) {
  int i = blockIdx.x * blockDim.x + threadIdx.x;
  int stride = gridDim.x * blockDim.x;
  for (; i < n4; i += stride) {
    float4 v = p[i];
    v.x = fmaxf(v.x, 0.f); v.y = fmaxf(v.y, 0.f);
    v.z = fmaxf(v.z, 0.f); v.w = fmaxf(v.w, 0.f);
    p[i] = v;
  }
}

__global__ __launch_bounds__(256) void spmm_atomic(const float* __restrict__ pre,
                                                   const int* __restrict__ src,
                                                   const int* __restrict__ dst,
                                                   const float* __restrict__ val,
                                                   float* __restrict__ out,
                                                   int n_edges) {
  const int lane = threadIdx.x & 63;
  const int wave = blockIdx.x * (blockDim.x >> 6) + (threadIdx.x >> 6);
  const int nwaves = gridDim.x * (blockDim.x >> 6);
  for (int e = wave; e < n_edges; e += nwaves) {
    int s = src[e];
    int d = dst[e];
    float v = val[e];
    const float2 p = *reinterpret_cast<const float2*>(&pre[(size_t)s * DOUT + lane * 2]);
    float* o = &out[(size_t)d * DOUT + lane * 2];
    atomicAdd(o, v * p.x);
    atomicAdd(o + 1, v * p.y);
  }
}

// ======================= host launch =======================

static inline size_t align_up(size_t v, size_t a) { return (v + a - 1) & ~(a - 1); }

extern "C" void kernel_launch(void* const* d_in, const int* in_sizes, int n_in,
                              void* d_out, int out_size, void* d_ws, size_t ws_size,
                              hipStream_t stream) {
  const float* x     = (const float*)d_in[0];
  const float* W     = (const float*)d_in[1];
  const int*   esrc  = (const int*)d_in[2];
  const int*   edst  = (const int*)d_in[3];
  const float* eval_ = (const float*)d_in[4];
  float* out = (float*)d_out;

  const int n_nodes    = in_sizes[0] / DIN;
  const int n_supports = in_sizes[1] / (DIN * DOUT);
  const int n_edges    = in_sizes[2] / n_supports;

  const int gemm_blocks = (n_nodes + 127) / 128;
  const int edge_blocks = (n_edges + 255) / 256;
  const int gather_blocks = (n_nodes + 3) / 4;

  // -------- tier 1: bf16 MFMA GEMM + merged bf16 gather --------
  {
    const int NR = n_supports * n_nodes;
    const int TE = n_supports * n_edges;
    const int scan_blocks = (NR + 2047) / 2048;
    char* w = (char*)d_ws;
    size_t off = 0;
    unsigned short* pre3 = (unsigned short*)(w + off); off += align_up((size_t)NR * DOUT * 2, 256);
    int* row_off = (int*)(w + off);    off += align_up((size_t)(NR + 1) * 4, 256);
    int* cursor = (int*)(w + off);     off += align_up((size_t)NR * 4, 256);
    int2* csr = (int2*)(w + off);      off += align_up((size_t)TE * 8, 256);
    int* partials = (int*)(w + off);   off += align_up(1024 * 4, 256);

    if (off <= ws_size && scan_blocks <= 256) {
      gemm_mfma<<<gemm_blocks, 256, 0, stream>>>(x, W, pre3, n_nodes, n_supports);
      hipMemsetAsync(cursor, 0, (size_t)NR * 4, stream);
      edge_hist<<<dim3(edge_blocks, n_supports), 256, 0, stream>>>(edst, cursor, n_edges, n_nodes);
      scan_local<<<scan_blocks, 256, 0, stream>>>(cursor, row_off, partials, NR);
      scan_partials_k<<<1, 256, 0, stream>>>(partials, scan_blocks);
      scan_finish<<<scan_blocks, 256, 0, stream>>>(row_off, cursor, partials, NR, TE);
      edge_fill<<<dim3(edge_blocks, n_supports), 256, 0, stream>>>(esrc, edst, eval_, cursor,
                                                                   csr, n_edges, n_nodes);
      spmm_gather_bf16<<<gather_blocks, 256, 0, stream>>>(pre3, csr, row_off, out,
                                                          n_nodes, n_supports);
      return;
    }
  }

  // -------- tier 2: fp32 per-support CSR gather --------
  {
    const int scan_blocks = (n_nodes + 2047) / 2048;
    char* w = (char*)d_ws;
    size_t off = 0;
    float* pre = (float*)(w + off);    off += align_up((size_t)n_nodes * DOUT * 4, 256);
    int* row_off = (int*)(w + off);    off += align_up((size_t)(n_nodes + 1) * 4, 256);
    int* cursor = (int*)(w + off);     off += align_up((size_t)n_nodes * 4, 256);
    int2* csr = (int2*)(w + off);      off += align_up((size_t)n_edges * 8, 256);
    int* partials = (int*)(w + off);   off += align_up(1024 * 4, 256);

    if (off <= ws_size && scan_blocks <= 256) {
      for (int s = 0; s < n_supports; ++s) {
        const int* src = esrc + (size_t)s * n_edges;
        const int* dst = edst + (size_t)s * n_edges;
        const float* val = eval_ + (size_t)s * n_edges;
        gemm_xw<<<dim3(gemm_blocks, 1), 256, 0, stream>>>(x, W + (size_t)s * DIN * DOUT,
                                                          pre, n_nodes);
        hipMemsetAsync(cursor, 0, (size_t)n_nodes * 4, stream);
        edge_hist<<<dim3(edge_blocks, 1), 256, 0, stream>>>(dst, cursor, n_edges, n_nodes);
        scan_local<<<scan_blocks, 256, 0, stream>>>(cursor, row_off, partials, n_nodes);
        scan_partials_k<<<1, 256, 0, stream>>>(partials, scan_blocks);
        scan_finish<<<scan_blocks, 256, 0, stream>>>(row_off, cursor, partials, n_nodes, n_edges);
        edge_fill<<<dim3(edge_blocks, 1), 256, 0, stream>>>(src, dst, val, cursor, csr,
                                                            n_edges, n_nodes);
        int mode = (s == 0) ? 0 : 1;
        if (s == n_supports - 1) mode |= 2;
        spmm_gather<<<gather_blocks, 256, 0, stream>>>(pre, csr, row_off, out,
                                                       n_nodes, 1, mode);
      }
      return;
    }
  }

  // -------- tier 3: atomic scatter --------
  {
    float* pre = (float*)d_ws;
    if (ws_size < (size_t)n_nodes * DOUT * 4) return;
    const int n4 = out_size / 4;
    zero_f4<<<2048, 256, 0, stream>>>((float4*)out, n4);
    for (int s = 0; s < n_supports; ++s) {
      gemm_xw<<<dim3(gemm_blocks, 1), 256, 0, stream>>>(x, W + (size_t)s * DIN * DOUT,
                                                        pre, n_nodes);
      spmm_atomic<<<2048, 256, 0, stream>>>(pre, esrc + (size_t)s * n_edges,
                                            edst + (size_t)s * n_edges,
                                            eval_ + (size_t)s * n_edges, out, n_edges);
    }
    relu_f4<<<2048, 256, 0, stream>>>((float4*)out, n4);
  }
}

// Round 5
// 331.079 us; speedup vs baseline: 4.3317x; 1.2467x over previous
//
#include <hip/hip_runtime.h>

#define DIN 128
#define DOUT 128

typedef __attribute__((ext_vector_type(8))) short short8;
typedef __attribute__((ext_vector_type(4))) float f32x4;
typedef __attribute__((ext_vector_type(8))) unsigned short ushort8;

__device__ __forceinline__ unsigned short f2bf(float f) {
  unsigned int u = __float_as_uint(f);
  u += 0x7fffu + ((u >> 16) & 1u);   // round-to-nearest-even
  return (unsigned short)(u >> 16);
}

// ======================= MFMA GEMM: pre[s] = bf16(x @ W[s]) =======================
// One block = 128-row tile, loops all supports internally. 256 thr = 4 waves.

__global__ __launch_bounds__(256) void gemm_mfma(const float* __restrict__ x,
                                                 const float* __restrict__ W,
                                                 unsigned short* __restrict__ pre,
                                                 int n_nodes, int n_sup) {
  __shared__ unsigned short xs[128][136];
  __shared__ unsigned short wt[128][136];

  const int tid = threadIdx.x;
  const int lane = tid & 63;
  const int w = tid >> 6;
  const int row0 = blockIdx.x * 128;
  const int alr = lane & 15;
  const int akg = lane >> 4;

#pragma unroll
  for (int i = 0; i < 16; ++i) {
    int e = tid + i * 256;
    int r = e >> 5;
    int c = (e & 31) * 4;
    int gr = row0 + r;
    float4 v = make_float4(0.f, 0.f, 0.f, 0.f);
    if (gr < n_nodes) v = *reinterpret_cast<const float4*>(&x[(size_t)gr * DIN + c]);
    xs[r][c] = f2bf(v.x); xs[r][c + 1] = f2bf(v.y);
    xs[r][c + 2] = f2bf(v.z); xs[r][c + 3] = f2bf(v.w);
  }
  __syncthreads();

  short8 afrag[4][2];
#pragma unroll
  for (int kc = 0; kc < 4; ++kc)
#pragma unroll
    for (int mt = 0; mt < 2; ++mt)
      afrag[kc][mt] = *reinterpret_cast<const short8*>(
          &xs[w * 32 + mt * 16 + alr][kc * 32 + akg * 8]);

  for (int s = 0; s < n_sup; ++s) {
    const float* Ws = W + (size_t)s * DIN * DOUT;
    __syncthreads();
#pragma unroll
    for (int i = 0; i < 16; ++i) {
      int e = tid + i * 256;
      int k = e >> 5;
      int c = (e & 31) * 4;
      float4 v = *reinterpret_cast<const float4*>(&Ws[(size_t)k * DOUT + c]);
      wt[c][k] = f2bf(v.x); wt[c + 1][k] = f2bf(v.y);
      wt[c + 2][k] = f2bf(v.z); wt[c + 3][k] = f2bf(v.w);
    }
    __syncthreads();

    f32x4 acc[2][8];
#pragma unroll
    for (int mt = 0; mt < 2; ++mt)
#pragma unroll
      for (int nt = 0; nt < 8; ++nt) acc[mt][nt] = (f32x4){0.f, 0.f, 0.f, 0.f};

#pragma unroll
    for (int kc = 0; kc < 4; ++kc) {
      short8 bfrag[8];
#pragma unroll
      for (int nt = 0; nt < 8; ++nt)
        bfrag[nt] = *reinterpret_cast<const short8*>(
            &wt[nt * 16 + alr][kc * 32 + akg * 8]);
#pragma unroll
      for (int mt = 0; mt < 2; ++mt)
#pragma unroll
        for (int nt = 0; nt < 8; ++nt)
          acc[mt][nt] = __builtin_amdgcn_mfma_f32_16x16x32_bf16(
              afrag[kc][mt], bfrag[nt], acc[mt][nt], 0, 0, 0);
    }
    __syncthreads();

#pragma unroll
    for (int mt = 0; mt < 2; ++mt)
#pragma unroll
      for (int nt = 0; nt < 8; ++nt)
#pragma unroll
        for (int q = 0; q < 4; ++q)
          wt[w * 32 + mt * 16 + akg * 4 + q][nt * 16 + alr] = f2bf(acc[mt][nt][q]);
    __syncthreads();

    unsigned short* ps = pre + (size_t)s * n_nodes * DOUT;
#pragma unroll
    for (int i = 0; i < 8; ++i) {
      int e = tid + i * 256;
      int r = e >> 4;
      int c = (e & 15) * 8;
      int gr = row0 + r;
      if (gr < n_nodes)
        *reinterpret_cast<ushort8*>(&ps[(size_t)gr * DOUT + c]) =
            *reinterpret_cast<const ushort8*>(&wt[r][c]);
    }
  }
}

// ======================= fp32 fallback GEMM (tiers 2/3) =======================

__global__ __launch_bounds__(256) void gemm_xw(const float* __restrict__ x,
                                               const float* __restrict__ W,
                                               float* __restrict__ pre,
                                               int n_nodes) {
  __shared__ float xsf[128][33];
  __shared__ float wtf[32][129];
  const float* Ws = W + (size_t)blockIdx.y * DIN * DOUT;
  float* pres = pre + (size_t)blockIdx.y * n_nodes * DOUT;
  const int tid = threadIdx.x;
  const int row0 = blockIdx.x * 128;
  const int tcol = tid & 15;
  const int trow = tid >> 4;
  float acc[8][8];
#pragma unroll
  for (int i = 0; i < 8; ++i)
#pragma unroll
    for (int j = 0; j < 8; ++j) acc[i][j] = 0.f;
#pragma unroll 1
  for (int kk = 0; kk < DIN; kk += 32) {
#pragma unroll
    for (int i = 0; i < 4; ++i) {
      int e = tid + i * 256;
      int r = e >> 3, c = (e & 7) * 4;
      int gr = row0 + r;
      float4 v = make_float4(0.f, 0.f, 0.f, 0.f);
      if (gr < n_nodes)
        v = *reinterpret_cast<const float4*>(&x[(size_t)gr * DIN + kk + c]);
      xsf[r][c] = v.x; xsf[r][c + 1] = v.y; xsf[r][c + 2] = v.z; xsf[r][c + 3] = v.w;
    }
#pragma unroll
    for (int i = 0; i < 4; ++i) {
      int e = tid + i * 256;
      int k = e >> 5, c = (e & 31) * 4;
      float4 v = *reinterpret_cast<const float4*>(&Ws[(size_t)(kk + k) * DOUT + c]);
      wtf[k][c] = v.x; wtf[k][c + 1] = v.y; wtf[k][c + 2] = v.z; wtf[k][c + 3] = v.w;
    }
    __syncthreads();
#pragma unroll 4
    for (int k = 0; k < 32; ++k) {
      float a[8], b[8];
#pragma unroll
      for (int i = 0; i < 8; ++i) a[i] = xsf[trow * 8 + i][k];
#pragma unroll
      for (int j = 0; j < 8; ++j) b[j] = wtf[k][tcol + 16 * j];
#pragma unroll
      for (int i = 0; i < 8; ++i)
#pragma unroll
        for (int j = 0; j < 8; ++j) acc[i][j] = fmaf(a[i], b[j], acc[i][j]);
    }
    __syncthreads();
  }
#pragma unroll
  for (int i = 0; i < 8; ++i) {
    int gr = row0 + trow * 8 + i;
    if (gr < n_nodes) {
#pragma unroll
      for (int j = 0; j < 8; ++j)
        pres[(size_t)gr * DOUT + tcol + 16 * j] = acc[i][j];
    }
  }
}

// ======================= merged CSR build (row = dst node) =======================

__global__ __launch_bounds__(256) void edge_hist_all(const int* __restrict__ dst_all,
                                                     int* __restrict__ counts,
                                                     int total_edges) {
  int i = blockIdx.x * blockDim.x + threadIdx.x;
  if (i < total_edges) atomicAdd(&counts[dst_all[i]], 1);
}

__global__ __launch_bounds__(256) void scan_local(const int* __restrict__ counts,
                                                  int* __restrict__ row_off,
                                                  int* __restrict__ partials, int n) {
  __shared__ int tmp[256];
  const int tid = threadIdx.x;
  const int base = blockIdx.x * 2048 + tid * 8;
  int v[8];
#pragma unroll
  for (int i = 0; i < 8; ++i) v[i] = (base + i < n) ? counts[base + i] : 0;
  int s = 0;
#pragma unroll
  for (int i = 0; i < 8; ++i) s += v[i];
  tmp[tid] = s;
  __syncthreads();
#pragma unroll
  for (int d = 1; d < 256; d <<= 1) {
    int t = (tid >= d) ? tmp[tid - d] : 0;
    __syncthreads();
    tmp[tid] += t;
    __syncthreads();
  }
  int p = tmp[tid] - s;
#pragma unroll
  for (int i = 0; i < 8; ++i) {
    if (base + i < n) row_off[base + i] = p;
    p += v[i];
  }
  if (tid == 255) partials[blockIdx.x] = tmp[255];
}

__global__ __launch_bounds__(256) void scan_partials_k(int* __restrict__ partials, int nblk) {
  __shared__ int tmp[256];
  const int tid = threadIdx.x;
  int v = (tid < nblk) ? partials[tid] : 0;
  tmp[tid] = v;
  __syncthreads();
#pragma unroll
  for (int d = 1; d < 256; d <<= 1) {
    int t = (tid >= d) ? tmp[tid - d] : 0;
    __syncthreads();
    tmp[tid] += t;
    __syncthreads();
  }
  if (tid < nblk) partials[tid] = tmp[tid] - v;
}

__global__ __launch_bounds__(256) void scan_finish(int* __restrict__ row_off,
                                                   int* __restrict__ cursor,
                                                   const int* __restrict__ partials,
                                                   int n, int total_edges) {
  const int off = partials[blockIdx.x];
  const int base = blockIdx.x * 2048 + threadIdx.x * 8;
#pragma unroll
  for (int i = 0; i < 8; ++i) {
    int idx = base + i;
    if (idx < n) {
      int v = row_off[idx] + off;
      row_off[idx] = v;
      cursor[idx] = v;
    }
  }
  if (blockIdx.x == 0 && threadIdx.x == 0) row_off[n] = total_edges;
}

// entry stores global pre-row (s*n_nodes + src) + value
__global__ __launch_bounds__(256) void edge_fill_all(const int* __restrict__ src_all,
                                                     const int* __restrict__ dst_all,
                                                     const float* __restrict__ val_all,
                                                     int* __restrict__ cursor,
                                                     int2* __restrict__ csr,
                                                     int n_edges, int n_nodes,
                                                     int total_edges) {
  int i = blockIdx.x * blockDim.x + threadIdx.x;
  if (i < total_edges) {
    int s = i / n_edges;
    int d = dst_all[i];
    int pos = atomicAdd(&cursor[d], 1);
    csr[pos] = make_int2(s * n_nodes + src_all[i], __float_as_int(val_all[i]));
  }
}

// ======================= gather: 8 edges in flight per wave =======================
// Wave = 8 groups x 8 lanes. Group g walks edges beg+g, beg+g+8, ...
// Lane t in a group reads 32 B (16 bf16 cols [t*16, t*16+16)) of the gathered row.

__global__ __launch_bounds__(256) void spmm_gather8(const unsigned short* __restrict__ pre,
                                                    const int2* __restrict__ csr,
                                                    const int* __restrict__ row_off,
                                                    float* __restrict__ out, int n_nodes) {
  const int lane = threadIdx.x & 63;
  const int g = lane >> 3;
  const int t = lane & 7;
  const int wave = blockIdx.x * (blockDim.x >> 6) + (threadIdx.x >> 6);
  const int nwaves = gridDim.x * (blockDim.x >> 6);

  for (int n = wave; n < n_nodes; n += nwaves) {
    const int beg = row_off[n];
    const int end = row_off[n + 1];
    float acc[16];
#pragma unroll
    for (int k = 0; k < 16; ++k) acc[k] = 0.f;

    for (int j = beg + g; j < end; j += 8) {
      const int2 e = csr[j];
      const float v = __int_as_float(e.y);
      const ushort8* pr =
          reinterpret_cast<const ushort8*>(&pre[(size_t)e.x * DOUT + t * 16]);
      ushort8 p0 = pr[0];
      ushort8 p1 = pr[1];
#pragma unroll
      for (int k = 0; k < 8; ++k) {
        acc[k]     = fmaf(v, __uint_as_float((unsigned int)(unsigned short)p0[k] << 16), acc[k]);
        acc[8 + k] = fmaf(v, __uint_as_float((unsigned int)(unsigned short)p1[k] << 16), acc[8 + k]);
      }
    }

    // butterfly sum across the 8 groups (lanes differing in bits 3..5)
#pragma unroll
    for (int d = 8; d <= 32; d <<= 1)
#pragma unroll
      for (int k = 0; k < 16; ++k) acc[k] += __shfl_xor(acc[k], d, 64);

    // lane (g,t) writes cols [t*16 + g*2, +2) — static-index select over g
    float r0 = 0.f, r1 = 0.f;
#pragma unroll
    for (int gg = 0; gg < 8; ++gg)
      if (gg == g) { r0 = acc[gg * 2]; r1 = acc[gg * 2 + 1]; }
    r0 = fmaxf(r0, 0.f);
    r1 = fmaxf(r1, 0.f);
    *reinterpret_cast<float2*>(&out[(size_t)n * DOUT + t * 16 + g * 2]) =
        make_float2(r0, r1);
  }
}

// ======================= tier-2/3 fallback kernels =======================

__global__ __launch_bounds__(256) void edge_hist(const int* __restrict__ dst_base,
                                                 int* __restrict__ counts,
                                                 int n_edges, int n_nodes) {
  int i = blockIdx.x * blockDim.x + threadIdx.x;
  int s = blockIdx.y;
  if (i < n_edges) atomicAdd(&counts[s * n_nodes + dst_base[(size_t)s * n_edges + i]], 1);
}

__global__ __launch_bounds__(256) void edge_fill(const int* __restrict__ src_base,
                                                 const int* __restrict__ dst_base,
                                                 const float* __restrict__ val_base,
                                                 int* __restrict__ cursor,
                                                 int2* __restrict__ csr,
                                                 int n_edges, int n_nodes) {
  int i = blockIdx.x * blockDim.x + threadIdx.x;
  int s = blockIdx.y;
  if (i < n_edges) {
    size_t gi = (size_t)s * n_edges + i;
    int d = dst_base[gi];
    int pos = atomicAdd(&cursor[s * n_nodes + d], 1);
    csr[pos] = make_int2(src_base[gi], __float_as_int(val_base[gi]));
  }
}

__global__ __launch_bounds__(256) void spmm_gather(const float* __restrict__ pre,
                                                   const int2* __restrict__ csr,
                                                   const int* __restrict__ row_off,
                                                   float* __restrict__ out,
                                                   int n_nodes, int n_sup, int mode) {
  const int lane = threadIdx.x & 63;
  const int wave = blockIdx.x * (blockDim.x >> 6) + (threadIdx.x >> 6);
  const int nwaves = gridDim.x * (blockDim.x >> 6);
  for (int n = wave; n < n_nodes; n += nwaves) {
    float ax = 0.f, ay = 0.f;
    float2* o = reinterpret_cast<float2*>(&out[(size_t)n * DOUT + lane * 2]);
    if (mode & 1) { float2 prev = *o; ax = prev.x; ay = prev.y; }
    for (int s = 0; s < n_sup; ++s) {
      const float* ps = pre + (size_t)s * n_nodes * DOUT;
      const int row = s * n_nodes + n;
      const int beg = row_off[row];
      const int end = row_off[row + 1];
      for (int j = beg; j < end; ++j) {
        const int2 e = csr[j];
        const float v = __int_as_float(e.y);
        const float2 p = *reinterpret_cast<const float2*>(&ps[(size_t)e.x * DOUT + lane * 2]);
        ax = fmaf(v, p.x, ax);
        ay = fmaf(v, p.y, ay);
      }
    }
    if (mode & 2) { ax = fmaxf(ax, 0.f); ay = fmaxf(ay, 0.f); }
    *o = make_float2(ax, ay);
  }
}

__global__ __launch_bounds__(256) void zero_f4(float4* __restrict__ p, int n4) {
  int i = blockIdx.x * blockDim.x + threadIdx.x;
  int stride = gridDim.x * blockDim.x;
  float4 z = make_float4(0.f, 0.f, 0.f, 0.f);
  for (; i < n4; i += stride) p[i] = z;
}

__global__ __launch_bounds__(256) void relu_f4(float4* __restrict__ p, int n4) {
  int i = blockIdx.x * blockDim.x + threadIdx.x;
  int stride = gridDim.x * blockDim.x;
  for (; i < n4; i += stride) {
    float4 v = p[i];
    v.x = fmaxf(v.x, 0.f); v.y = fmaxf(v.y, 0.f);
    v.z = fmaxf(v.z, 0.f); v.w = fmaxf(v.w, 0.f);
    p[i] = v;
  }
}

__global__ __launch_bounds__(256) void spmm_atomic(const float* __restrict__ pre,
                                                   const int* __restrict__ src,
                                                   const int* __restrict__ dst,
                                                   const float* __restrict__ val,
                                                   float* __restrict__ out,
                                                   int n_edges) {
  const int lane = threadIdx.x & 63;
  const int wave = blockIdx.x * (blockDim.x >> 6) + (threadIdx.x >> 6);
  const int nwaves = gridDim.x * (blockDim.x >> 6);
  for (int e = wave; e < n_edges; e += nwaves) {
    int s = src[e];
    int d = dst[e];
    float v = val[e];
    const float2 p = *reinterpret_cast<const float2*>(&pre[(size_t)s * DOUT + lane * 2]);
    float* o = &out[(size_t)d * DOUT + lane * 2];
    atomicAdd(o, v * p.x);
    atomicAdd(o + 1, v * p.y);
  }
}

// ======================= host launch =======================

static inline size_t align_up(size_t v, size_t a) { return (v + a - 1) & ~(a - 1); }

extern "C" void kernel_launch(void* const* d_in, const int* in_sizes, int n_in,
                              void* d_out, int out_size, void* d_ws, size_t ws_size,
                              hipStream_t stream) {
  const float* x     = (const float*)d_in[0];
  const float* W     = (const float*)d_in[1];
  const int*   esrc  = (const int*)d_in[2];
  const int*   edst  = (const int*)d_in[3];
  const float* eval_ = (const float*)d_in[4];
  float* out = (float*)d_out;

  const int n_nodes    = in_sizes[0] / DIN;
  const int n_supports = in_sizes[1] / (DIN * DOUT);
  const int n_edges    = in_sizes[2] / n_supports;

  const int gemm_blocks = (n_nodes + 127) / 128;
  const int edge_blocks = (n_edges + 255) / 256;
  const int gather_blocks = (n_nodes + 3) / 4;

  // -------- tier 1: bf16 MFMA GEMM + merged-CSR 8-way gather --------
  {
    const int NR = n_supports * n_nodes;           // pre rows
    const int TE = n_supports * n_edges;           // total edges
    const int scan_blocks = (n_nodes + 2047) / 2048;
    const int te_blocks = (TE + 255) / 256;
    char* w = (char*)d_ws;
    size_t off = 0;
    unsigned short* pre3 = (unsigned short*)(w + off); off += align_up((size_t)NR * DOUT * 2, 256);
    int* row_off = (int*)(w + off);    off += align_up((size_t)(n_nodes + 1) * 4, 256);
    int* cursor = (int*)(w + off);     off += align_up((size_t)n_nodes * 4, 256);
    int2* csr = (int2*)(w + off);      off += align_up((size_t)TE * 8, 256);
    int* partials = (int*)(w + off);   off += align_up(1024 * 4, 256);

    if (off <= ws_size && scan_blocks <= 256) {
      gemm_mfma<<<gemm_blocks, 256, 0, stream>>>(x, W, pre3, n_nodes, n_supports);
      hipMemsetAsync(cursor, 0, (size_t)n_nodes * 4, stream);
      edge_hist_all<<<te_blocks, 256, 0, stream>>>(edst, cursor, TE);
      scan_local<<<scan_blocks, 256, 0, stream>>>(cursor, row_off, partials, n_nodes);
      scan_partials_k<<<1, 256, 0, stream>>>(partials, scan_blocks);
      scan_finish<<<scan_blocks, 256, 0, stream>>>(row_off, cursor, partials, n_nodes, TE);
      edge_fill_all<<<te_blocks, 256, 0, stream>>>(esrc, edst, eval_, cursor, csr,
                                                   n_edges, n_nodes, TE);
      spmm_gather8<<<gather_blocks, 256, 0, stream>>>(pre3, csr, row_off, out, n_nodes);
      return;
    }
  }

  // -------- tier 2: fp32 per-support CSR gather --------
  {
    const int scan_blocks = (n_nodes + 2047) / 2048;
    char* w = (char*)d_ws;
    size_t off = 0;
    float* pre = (float*)(w + off);    off += align_up((size_t)n_nodes * DOUT * 4, 256);
    int* row_off = (int*)(w + off);    off += align_up((size_t)(n_nodes + 1) * 4, 256);
    int* cursor = (int*)(w + off);     off += align_up((size_t)n_nodes * 4, 256);
    int2* csr = (int2*)(w + off);      off += align_up((size_t)n_edges * 8, 256);
    int* partials = (int*)(w + off);   off += align_up(1024 * 4, 256);

    if (off <= ws_size && scan_blocks <= 256) {
      for (int s = 0; s < n_supports; ++s) {
        const int* src = esrc + (size_t)s * n_edges;
        const int* dst = edst + (size_t)s * n_edges;
        const float* val = eval_ + (size_t)s * n_edges;
        gemm_xw<<<dim3(gemm_blocks, 1), 256, 0, stream>>>(x, W + (size_t)s * DIN * DOUT,
                                                          pre, n_nodes);
        hipMemsetAsync(cursor, 0, (size_t)n_nodes * 4, stream);
        edge_hist<<<dim3(edge_blocks, 1), 256, 0, stream>>>(dst, cursor, n_edges, n_nodes);
        scan_local<<<scan_blocks, 256, 0, stream>>>(cursor, row_off, partials, n_nodes);
        scan_partials_k<<<1, 256, 0, stream>>>(partials, scan_blocks);
        scan_finish<<<scan_blocks, 256, 0, stream>>>(row_off, cursor, partials, n_nodes, n_edges);
        edge_fill<<<dim3(edge_blocks, 1), 256, 0, stream>>>(src, dst, val, cursor, csr,
                                                            n_edges, n_nodes);
        int mode = (s == 0) ? 0 : 1;
        if (s == n_supports - 1) mode |= 2;
        spmm_gather<<<gather_blocks, 256, 0, stream>>>(pre, csr, row_off, out,
                                                       n_nodes, 1, mode);
      }
      return;
    }
  }

  // -------- tier 3: atomic scatter --------
  {
    float* pre = (float*)d_ws;
    if (ws_size < (size_t)n_nodes * DOUT * 4) return;
    const int n4 = out_size / 4;
    zero_f4<<<2048, 256, 0, stream>>>((float4*)out, n4);
    for (int s = 0; s < n_supports; ++s) {
      gemm_xw<<<dim3(gemm_blocks, 1), 256, 0, stream>>>(x, W + (size_t)s * DIN * DOUT,
                                                        pre, n_nodes);
      spmm_atomic<<<2048, 256, 0, stream>>>(pre, esrc + (size_t)s * n_edges,
                                            edst + (size_t)s * n_edges,
                                            eval_ + (size_t)s * n_edges, out, n_edges);
    }
    relu_f4<<<2048, 256, 0, stream>>>((float4*)out, n4);
  }
}

// Round 6
// 200.349 us; speedup vs baseline: 7.1582x; 1.6525x over previous
//
#include <hip/hip_runtime.h>

#define DIN 128
#define DOUT 128
#define EPB 4096            // edges per block for count/partition
#define BKT 512             // nodes per bucket (dst >> 9)
#define PACK_BITS 19        // src_global bits; dst_low in bits 19..27
#define SRCG_MASK ((1u << PACK_BITS) - 1u)

typedef __attribute__((ext_vector_type(8))) short short8;
typedef __attribute__((ext_vector_type(4))) float f32x4;
typedef __attribute__((ext_vector_type(8))) unsigned short ushort8;

__device__ __forceinline__ unsigned short f2bf(float f) {
  unsigned int u = __float_as_uint(f);
  u += 0x7fffu + ((u >> 16) & 1u);   // round-to-nearest-even
  return (unsigned short)(u >> 16);
}

// ======================= MFMA GEMM: pre[s] = bf16(x @ W[s]) =======================

__global__ __launch_bounds__(256) void gemm_mfma(const float* __restrict__ x,
                                                 const float* __restrict__ W,
                                                 unsigned short* __restrict__ pre,
                                                 int n_nodes, int n_sup) {
  __shared__ unsigned short xs[128][136];
  __shared__ unsigned short wt[128][136];

  const int tid = threadIdx.x;
  const int lane = tid & 63;
  const int w = tid >> 6;
  const int row0 = blockIdx.x * 128;
  const int alr = lane & 15;
  const int akg = lane >> 4;

#pragma unroll
  for (int i = 0; i < 16; ++i) {
    int e = tid + i * 256;
    int r = e >> 5;
    int c = (e & 31) * 4;
    int gr = row0 + r;
    float4 v = make_float4(0.f, 0.f, 0.f, 0.f);
    if (gr < n_nodes) v = *reinterpret_cast<const float4*>(&x[(size_t)gr * DIN + c]);
    xs[r][c] = f2bf(v.x); xs[r][c + 1] = f2bf(v.y);
    xs[r][c + 2] = f2bf(v.z); xs[r][c + 3] = f2bf(v.w);
  }
  __syncthreads();

  short8 afrag[4][2];
#pragma unroll
  for (int kc = 0; kc < 4; ++kc)
#pragma unroll
    for (int mt = 0; mt < 2; ++mt)
      afrag[kc][mt] = *reinterpret_cast<const short8*>(
          &xs[w * 32 + mt * 16 + alr][kc * 32 + akg * 8]);

  for (int s = 0; s < n_sup; ++s) {
    const float* Ws = W + (size_t)s * DIN * DOUT;
    __syncthreads();
#pragma unroll
    for (int i = 0; i < 16; ++i) {
      int e = tid + i * 256;
      int k = e >> 5;
      int c = (e & 31) * 4;
      float4 v = *reinterpret_cast<const float4*>(&Ws[(size_t)k * DOUT + c]);
      wt[c][k] = f2bf(v.x); wt[c + 1][k] = f2bf(v.y);
      wt[c + 2][k] = f2bf(v.z); wt[c + 3][k] = f2bf(v.w);
    }
    __syncthreads();

    f32x4 acc[2][8];
#pragma unroll
    for (int mt = 0; mt < 2; ++mt)
#pragma unroll
      for (int nt = 0; nt < 8; ++nt) acc[mt][nt] = (f32x4){0.f, 0.f, 0.f, 0.f};

#pragma unroll
    for (int kc = 0; kc < 4; ++kc) {
      short8 bfrag[8];
#pragma unroll
      for (int nt = 0; nt < 8; ++nt)
        bfrag[nt] = *reinterpret_cast<const short8*>(
            &wt[nt * 16 + alr][kc * 32 + akg * 8]);
#pragma unroll
      for (int mt = 0; mt < 2; ++mt)
#pragma unroll
        for (int nt = 0; nt < 8; ++nt)
          acc[mt][nt] = __builtin_amdgcn_mfma_f32_16x16x32_bf16(
              afrag[kc][mt], bfrag[nt], acc[mt][nt], 0, 0, 0);
    }
    __syncthreads();

#pragma unroll
    for (int mt = 0; mt < 2; ++mt)
#pragma unroll
      for (int nt = 0; nt < 8; ++nt)
#pragma unroll
        for (int q = 0; q < 4; ++q)
          wt[w * 32 + mt * 16 + akg * 4 + q][nt * 16 + alr] = f2bf(acc[mt][nt][q]);
    __syncthreads();

    unsigned short* ps = pre + (size_t)s * n_nodes * DOUT;
#pragma unroll
    for (int i = 0; i < 8; ++i) {
      int e = tid + i * 256;
      int r = e >> 4;
      int c = (e & 15) * 8;
      int gr = row0 + r;
      if (gr < n_nodes)
        *reinterpret_cast<ushort8*>(&ps[(size_t)gr * DOUT + c]) =
            *reinterpret_cast<const ushort8*>(&wt[r][c]);
    }
  }
}

// ======================= fp32 fallback GEMM (tiers 2/3) =======================

__global__ __launch_bounds__(256) void gemm_xw(const float* __restrict__ x,
                                               const float* __restrict__ W,
                                               float* __restrict__ pre,
                                               int n_nodes) {
  __shared__ float xsf[128][33];
  __shared__ float wtf[32][129];
  const float* Ws = W + (size_t)blockIdx.y * DIN * DOUT;
  float* pres = pre + (size_t)blockIdx.y * n_nodes * DOUT;
  const int tid = threadIdx.x;
  const int row0 = blockIdx.x * 128;
  const int tcol = tid & 15;
  const int trow = tid >> 4;
  float acc[8][8];
#pragma unroll
  for (int i = 0; i < 8; ++i)
#pragma unroll
    for (int j = 0; j < 8; ++j) acc[i][j] = 0.f;
#pragma unroll 1
  for (int kk = 0; kk < DIN; kk += 32) {
#pragma unroll
    for (int i = 0; i < 4; ++i) {
      int e = tid + i * 256;
      int r = e >> 3, c = (e & 7) * 4;
      int gr = row0 + r;
      float4 v = make_float4(0.f, 0.f, 0.f, 0.f);
      if (gr < n_nodes)
        v = *reinterpret_cast<const float4*>(&x[(size_t)gr * DIN + kk + c]);
      xsf[r][c] = v.x; xsf[r][c + 1] = v.y; xsf[r][c + 2] = v.z; xsf[r][c + 3] = v.w;
    }
#pragma unroll
    for (int i = 0; i < 4; ++i) {
      int e = tid + i * 256;
      int k = e >> 5, c = (e & 31) * 4;
      float4 v = *reinterpret_cast<const float4*>(&Ws[(size_t)(kk + k) * DOUT + c]);
      wtf[k][c] = v.x; wtf[k][c + 1] = v.y; wtf[k][c + 2] = v.z; wtf[k][c + 3] = v.w;
    }
    __syncthreads();
#pragma unroll 4
    for (int k = 0; k < 32; ++k) {
      float a[8], b[8];
#pragma unroll
      for (int i = 0; i < 8; ++i) a[i] = xsf[trow * 8 + i][k];
#pragma unroll
      for (int j = 0; j < 8; ++j) b[j] = wtf[k][tcol + 16 * j];
#pragma unroll
      for (int i = 0; i < 8; ++i)
#pragma unroll
        for (int j = 0; j < 8; ++j) acc[i][j] = fmaf(a[i], b[j], acc[i][j]);
    }
    __syncthreads();
  }
#pragma unroll
  for (int i = 0; i < 8; ++i) {
    int gr = row0 + trow * 8 + i;
    if (gr < n_nodes) {
#pragma unroll
      for (int j = 0; j < 8; ++j)
        pres[(size_t)gr * DOUT + tcol + 16 * j] = acc[i][j];
    }
  }
}

// ======================= bucketed CSR build =======================
// bucket b = dst >> 9 (512 nodes each). NB <= 256.

__global__ __launch_bounds__(256) void bucket_count(const int* __restrict__ dst_all,
                                                    int* __restrict__ bucket_cnt, int TE) {
  __shared__ int cnt[256];
  const int tid = threadIdx.x;
  cnt[tid] = 0;
  __syncthreads();
  const int beg = blockIdx.x * EPB;
  const int end = min(beg + EPB, TE);
  for (int i = beg + tid; i < end; i += 256) atomicAdd(&cnt[dst_all[i] >> 9], 1);
  __syncthreads();
  int c = cnt[tid];
  if (c) atomicAdd(&bucket_cnt[tid], c);
}

// single block: exclusive scan of NB bucket counts -> base/cursor; base[NB]=TE
__global__ __launch_bounds__(256) void bucket_scan(const int* __restrict__ bucket_cnt,
                                                   int* __restrict__ bucket_base,
                                                   int* __restrict__ bucket_cursor,
                                                   int NB, int TE) {
  __shared__ int tmp[256];
  const int tid = threadIdx.x;
  int v = (tid < NB) ? bucket_cnt[tid] : 0;
  tmp[tid] = v;
  __syncthreads();
#pragma unroll
  for (int d = 1; d < 256; d <<= 1) {
    int t = (tid >= d) ? tmp[tid - d] : 0;
    __syncthreads();
    tmp[tid] += t;
    __syncthreads();
  }
  int excl = tmp[tid] - v;
  if (tid < NB) {
    bucket_base[tid] = excl;
    bucket_cursor[tid] = excl;
  }
  if (tid == 0) bucket_base[NB] = TE;
}

// partition edges into bucket-contiguous order; entry = {src_g | dst_low<<19, val}
__global__ __launch_bounds__(256) void partition_edges(const int* __restrict__ src_all,
                                                       const int* __restrict__ dst_all,
                                                       const float* __restrict__ val_all,
                                                       int* __restrict__ bucket_cursor,
                                                       int2* __restrict__ part,
                                                       int TE, int n_nodes, int n_edges) {
  __shared__ int cnt[256];
  __shared__ int base_l[256];
  const int tid = threadIdx.x;
  const int beg = blockIdx.x * EPB;
  const int end = min(beg + EPB, TE);

  cnt[tid] = 0;
  __syncthreads();
  for (int i = beg + tid; i < end; i += 256) atomicAdd(&cnt[dst_all[i] >> 9], 1);
  __syncthreads();

  int c = cnt[tid];
  int mybase = (c > 0) ? atomicAdd(&bucket_cursor[tid], c) : 0;
  __syncthreads();
  base_l[tid] = mybase;
  cnt[tid] = 0;
  __syncthreads();

  for (int i = beg + tid; i < end; i += 256) {
    int d = dst_all[i];
    int b = d >> 9;
    int r = atomicAdd(&cnt[b], 1);
    int s = i / n_edges;
    unsigned key = (unsigned)(s * n_nodes + src_all[i]) |
                   ((unsigned)(d & (BKT - 1)) << PACK_BITS);
    part[base_l[b] + r] = make_int2((int)key, __float_as_int(val_all[i]));
  }
}

// one block per bucket: per-node hist+scan in LDS, write row_off, scatter csr locally
__global__ __launch_bounds__(256) void csr_build(const int2* __restrict__ part,
                                                 const int* __restrict__ bucket_base,
                                                 int2* __restrict__ csr,
                                                 int* __restrict__ row_off,
                                                 int n_nodes, int TE) {
  __shared__ int cnt[BKT];
  __shared__ int off_s[BKT];
  __shared__ int tmp[256];
  const int b = blockIdx.x;
  const int tid = threadIdx.x;
  const int bb = bucket_base[b];
  const int be = bucket_base[b + 1];

  cnt[tid] = 0;
  cnt[tid + 256] = 0;
  __syncthreads();
  for (int j = bb + tid; j < be; j += 256)
    atomicAdd(&cnt[((unsigned)part[j].x) >> PACK_BITS], 1);
  __syncthreads();

  // exclusive scan of 512 counters via pair-sums
  int s2 = cnt[2 * tid] + cnt[2 * tid + 1];
  tmp[tid] = s2;
  __syncthreads();
#pragma unroll
  for (int d = 1; d < 256; d <<= 1) {
    int t = (tid >= d) ? tmp[tid - d] : 0;
    __syncthreads();
    tmp[tid] += t;
    __syncthreads();
  }
  int excl2 = tmp[tid] - s2;
  off_s[2 * tid] = excl2;
  off_s[2 * tid + 1] = excl2 + cnt[2 * tid];
  __syncthreads();

  // row_off (coalesced) + reset cnt as local cursor
#pragma unroll
  for (int k = tid; k < BKT; k += 256) {
    int node = b * BKT + k;
    if (node < n_nodes) row_off[node] = bb + off_s[k];
  }
  cnt[tid] = off_s[tid];
  cnt[tid + 256] = off_s[tid + 256];
  __syncthreads();

  for (int j = bb + tid; j < be; j += 256) {
    int2 e = part[j];
    int dl = ((unsigned)e.x) >> PACK_BITS;
    int p = bb + atomicAdd(&cnt[dl], 1);
    csr[p] = e;
  }
  if (b == 0 && tid == 0) row_off[n_nodes] = TE;
}

// ======================= gather: 8 edges in flight per wave =======================

__global__ __launch_bounds__(256) void spmm_gather8(const unsigned short* __restrict__ pre,
                                                    const int2* __restrict__ csr,
                                                    const int* __restrict__ row_off,
                                                    float* __restrict__ out, int n_nodes) {
  const int lane = threadIdx.x & 63;
  const int g = lane >> 3;
  const int t = lane & 7;
  const int wave = blockIdx.x * (blockDim.x >> 6) + (threadIdx.x >> 6);
  const int nwaves = gridDim.x * (blockDim.x >> 6);

  for (int n = wave; n < n_nodes; n += nwaves) {
    const int beg = row_off[n];
    const int end = row_off[n + 1];
    float acc[16];
#pragma unroll
    for (int k = 0; k < 16; ++k) acc[k] = 0.f;

    for (int j = beg + g; j < end; j += 8) {
      const int2 e = csr[j];
      const float v = __int_as_float(e.y);
      const unsigned srcg = ((unsigned)e.x) & SRCG_MASK;
      const ushort8* pr =
          reinterpret_cast<const ushort8*>(&pre[(size_t)srcg * DOUT + t * 16]);
      ushort8 p0 = pr[0];
      ushort8 p1 = pr[1];
#pragma unroll
      for (int k = 0; k < 8; ++k) {
        acc[k]     = fmaf(v, __uint_as_float((unsigned int)(unsigned short)p0[k] << 16), acc[k]);
        acc[8 + k] = fmaf(v, __uint_as_float((unsigned int)(unsigned short)p1[k] << 16), acc[8 + k]);
      }
    }

#pragma unroll
    for (int d = 8; d <= 32; d <<= 1)
#pragma unroll
      for (int k = 0; k < 16; ++k) acc[k] += __shfl_xor(acc[k], d, 64);

    float r0 = 0.f, r1 = 0.f;
#pragma unroll
    for (int gg = 0; gg < 8; ++gg)
      if (gg == g) { r0 = acc[gg * 2]; r1 = acc[gg * 2 + 1]; }
    r0 = fmaxf(r0, 0.f);
    r1 = fmaxf(r1, 0.f);
    *reinterpret_cast<float2*>(&out[(size_t)n * DOUT + t * 16 + g * 2]) =
        make_float2(r0, r1);
  }
}

// ======================= tier-2/3 fallback kernels =======================

__global__ __launch_bounds__(256) void edge_hist(const int* __restrict__ dst_base,
                                                 int* __restrict__ counts,
                                                 int n_edges, int n_nodes) {
  int i = blockIdx.x * blockDim.x + threadIdx.x;
  int s = blockIdx.y;
  if (i < n_edges) atomicAdd(&counts[s * n_nodes + dst_base[(size_t)s * n_edges + i]], 1);
}

__global__ __launch_bounds__(256) void scan_local(const int* __restrict__ counts,
                                                  int* __restrict__ row_off,
                                                  int* __restrict__ partials, int n) {
  __shared__ int tmp[256];
  const int tid = threadIdx.x;
  const int base = blockIdx.x * 2048 + tid * 8;
  int v[8];
#pragma unroll
  for (int i = 0; i < 8; ++i) v[i] = (base + i < n) ? counts[base + i] : 0;
  int s = 0;
#pragma unroll
  for (int i = 0; i < 8; ++i) s += v[i];
  tmp[tid] = s;
  __syncthreads();
#pragma unroll
  for (int d = 1; d < 256; d <<= 1) {
    int t = (tid >= d) ? tmp[tid - d] : 0;
    __syncthreads();
    tmp[tid] += t;
    __syncthreads();
  }
  int p = tmp[tid] - s;
#pragma unroll
  for (int i = 0; i < 8; ++i) {
    if (base + i < n) row_off[base + i] = p;
    p += v[i];
  }
  if (tid == 255) partials[blockIdx.x] = tmp[255];
}

__global__ __launch_bounds__(256) void scan_partials_k(int* __restrict__ partials, int nblk) {
  __shared__ int tmp[256];
  const int tid = threadIdx.x;
  int v = (tid < nblk) ? partials[tid] : 0;
  tmp[tid] = v;
  __syncthreads();
#pragma unroll
  for (int d = 1; d < 256; d <<= 1) {
    int t = (tid >= d) ? tmp[tid - d] : 0;
    __syncthreads();
    tmp[tid] += t;
    __syncthreads();
  }
  if (tid < nblk) partials[tid] = tmp[tid] - v;
}

__global__ __launch_bounds__(256) void scan_finish(int* __restrict__ row_off,
                                                   int* __restrict__ cursor,
                                                   const int* __restrict__ partials,
                                                   int n, int total_edges) {
  const int off = partials[blockIdx.x];
  const int base = blockIdx.x * 2048 + threadIdx.x * 8;
#pragma unroll
  for (int i = 0; i < 8; ++i) {
    int idx = base + i;
    if (idx < n) {
      int v = row_off[idx] + off;
      row_off[idx] = v;
      cursor[idx] = v;
    }
  }
  if (blockIdx.x == 0 && threadIdx.x == 0) row_off[n] = total_edges;
}

__global__ __launch_bounds__(256) void edge_fill(const int* __restrict__ src_base,
                                                 const int* __restrict__ dst_base,
                                                 const float* __restrict__ val_base,
                                                 int* __restrict__ cursor,
                                                 int2* __restrict__ csr,
                                                 int n_edges, int n_nodes) {
  int i = blockIdx.x * blockDim.x + threadIdx.x;
  int s = blockIdx.y;
  if (i < n_edges) {
    size_t gi = (size_t)s * n_edges + i;
    int d = dst_base[gi];
    int pos = atomicAdd(&cursor[s * n_nodes + d], 1);
    csr[pos] = make_int2(src_base[gi], __float_as_int(val_base[gi]));
  }
}

__global__ __launch_bounds__(256) void spmm_gather(const float* __restrict__ pre,
                                                   const int2* __restrict__ csr,
                                                   const int* __restrict__ row_off,
                                                   float* __restrict__ out,
                                                   int n_nodes, int n_sup, int mode) {
  const int lane = threadIdx.x & 63;
  const int wave = blockIdx.x * (blockDim.x >> 6) + (threadIdx.x >> 6);
  const int nwaves = gridDim.x * (blockDim.x >> 6);
  for (int n = wave; n < n_nodes; n += nwaves) {
    float ax = 0.f, ay = 0.f;
    float2* o = reinterpret_cast<float2*>(&out[(size_t)n * DOUT + lane * 2]);
    if (mode & 1) { float2 prev = *o; ax = prev.x; ay = prev.y; }
    for (int s = 0; s < n_sup; ++s) {
      const float* ps = pre + (size_t)s * n_nodes * DOUT;
      const int row = s * n_nodes + n;
      const int beg = row_off[row];
      const int end = row_off[row + 1];
      for (int j = beg; j < end; ++j) {
        const int2 e = csr[j];
        const float v = __int_as_float(e.y);
        const float2 p = *reinterpret_cast<const float2*>(&ps[(size_t)e.x * DOUT + lane * 2]);
        ax = fmaf(v, p.x, ax);
        ay = fmaf(v, p.y, ay);
      }
    }
    if (mode & 2) { ax = fmaxf(ax, 0.f); ay = fmaxf(ay, 0.f); }
    *o = make_float2(ax, ay);
  }
}

__global__ __launch_bounds__(256) void zero_f4(float4* __restrict__ p, int n4) {
  int i = blockIdx.x * blockDim.x + threadIdx.x;
  int stride = gridDim.x * blockDim.x;
  float4 z = make_float4(0.f, 0.f, 0.f, 0.f);
  for (; i < n4; i += stride) p[i] = z;
}

__global__ __launch_bounds__(256) void relu_f4(float4* __restrict__ p, int n4) {
  int i = blockIdx.x * blockDim.x + threadIdx.x;
  int stride = gridDim.x * blockDim.x;
  for (; i < n4; i += stride) {
    float4 v = p[i];
    v.x = fmaxf(v.x, 0.f); v.y = fmaxf(v.y, 0.f);
    v.z = fmaxf(v.z, 0.f); v.w = fmaxf(v.w, 0.f);
    p[i] = v;
  }
}

__global__ __launch_bounds__(256) void spmm_atomic(const float* __restrict__ pre,
                                                   const int* __restrict__ src,
                                                   const int* __restrict__ dst,
                                                   const float* __restrict__ val,
                                                   float* __restrict__ out,
                                                   int n_edges) {
  const int lane = threadIdx.x & 63;
  const int wave = blockIdx.x * (blockDim.x >> 6) + (threadIdx.x >> 6);
  const int nwaves = gridDim.x * (blockDim.x >> 6);
  for (int e = wave; e < n_edges; e += nwaves) {
    int s = src[e];
    int d = dst[e];
    float v = val[e];
    const float2 p = *reinterpret_cast<const float2*>(&pre[(size_t)s * DOUT + lane * 2]);
    float* o = &out[(size_t)d * DOUT + lane * 2];
    atomicAdd(o, v * p.x);
    atomicAdd(o + 1, v * p.y);
  }
}

// ======================= host launch =======================

static inline size_t align_up(size_t v, size_t a) { return (v + a - 1) & ~(a - 1); }

extern "C" void kernel_launch(void* const* d_in, const int* in_sizes, int n_in,
                              void* d_out, int out_size, void* d_ws, size_t ws_size,
                              hipStream_t stream) {
  const float* x     = (const float*)d_in[0];
  const float* W     = (const float*)d_in[1];
  const int*   esrc  = (const int*)d_in[2];
  const int*   edst  = (const int*)d_in[3];
  const float* eval_ = (const float*)d_in[4];
  float* out = (float*)d_out;

  const int n_nodes    = in_sizes[0] / DIN;
  const int n_supports = in_sizes[1] / (DIN * DOUT);
  const int n_edges    = in_sizes[2] / n_supports;

  const int gemm_blocks = (n_nodes + 127) / 128;
  const int edge_blocks = (n_edges + 255) / 256;
  const int gather_blocks = (n_nodes + 3) / 4;

  // -------- tier 1: MFMA GEMM + bucketed CSR + 8-way gather --------
  {
    const int NR = n_supports * n_nodes;
    const int TE = n_supports * n_edges;
    const int NB = (n_nodes + BKT - 1) / BKT;
    const int eb = (TE + EPB - 1) / EPB;
    char* w = (char*)d_ws;
    size_t off = 0;
    unsigned short* pre3 = (unsigned short*)(w + off); off += align_up((size_t)NR * DOUT * 2, 256);
    int* row_off = (int*)(w + off);      off += align_up((size_t)(n_nodes + 1) * 4, 256);
    int2* part = (int2*)(w + off);       off += align_up((size_t)TE * 8, 256);
    int2* csr = (int2*)(w + off);        off += align_up((size_t)TE * 8, 256);
    int* bucket_cnt = (int*)(w + off);   off += align_up(256 * 4, 256);
    int* bucket_base = (int*)(w + off);  off += align_up(257 * 4, 256);
    int* bucket_cur = (int*)(w + off);   off += align_up(256 * 4, 256);

    const bool packable = (size_t)n_supports * n_nodes < (1u << PACK_BITS);

    if (off <= ws_size && NB <= 256 && packable) {
      gemm_mfma<<<gemm_blocks, 256, 0, stream>>>(x, W, pre3, n_nodes, n_supports);
      hipMemsetAsync(bucket_cnt, 0, 256 * 4, stream);
      bucket_count<<<eb, 256, 0, stream>>>(edst, bucket_cnt, TE);
      bucket_scan<<<1, 256, 0, stream>>>(bucket_cnt, bucket_base, bucket_cur, NB, TE);
      partition_edges<<<eb, 256, 0, stream>>>(esrc, edst, eval_, bucket_cur, part,
                                              TE, n_nodes, n_edges);
      csr_build<<<NB, 256, 0, stream>>>(part, bucket_base, csr, row_off, n_nodes, TE);
      spmm_gather8<<<gather_blocks, 256, 0, stream>>>(pre3, csr, row_off, out, n_nodes);
      return;
    }
  }

  // -------- tier 2: fp32 per-support CSR gather --------
  {
    const int scan_blocks = (n_nodes + 2047) / 2048;
    char* w = (char*)d_ws;
    size_t off = 0;
    float* pre = (float*)(w + off);    off += align_up((size_t)n_nodes * DOUT * 4, 256);
    int* row_off = (int*)(w + off);    off += align_up((size_t)(n_nodes + 1) * 4, 256);
    int* cursor = (int*)(w + off);     off += align_up((size_t)n_nodes * 4, 256);
    int2* csr = (int2*)(w + off);      off += align_up((size_t)n_edges * 8, 256);
    int* partials = (int*)(w + off);   off += align_up(1024 * 4, 256);

    if (off <= ws_size && scan_blocks <= 256) {
      for (int s = 0; s < n_supports; ++s) {
        const int* src = esrc + (size_t)s * n_edges;
        const int* dst = edst + (size_t)s * n_edges;
        const float* val = eval_ + (size_t)s * n_edges;
        gemm_xw<<<dim3(gemm_blocks, 1), 256, 0, stream>>>(x, W + (size_t)s * DIN * DOUT,
                                                          pre, n_nodes);
        hipMemsetAsync(cursor, 0, (size_t)n_nodes * 4, stream);
        edge_hist<<<dim3(edge_blocks, 1), 256, 0, stream>>>(dst, cursor, n_edges, n_nodes);
        scan_local<<<scan_blocks, 256, 0, stream>>>(cursor, row_off, partials, n_nodes);
        scan_partials_k<<<1, 256, 0, stream>>>(partials, scan_blocks);
        scan_finish<<<scan_blocks, 256, 0, stream>>>(row_off, cursor, partials, n_nodes, n_edges);
        edge_fill<<<dim3(edge_blocks, 1), 256, 0, stream>>>(src, dst, val, cursor, csr,
                                                            n_edges, n_nodes);
        int mode = (s == 0) ? 0 : 1;
        if (s == n_supports - 1) mode |= 2;
        spmm_gather<<<gather_blocks, 256, 0, stream>>>(pre, csr, row_off, out,
                                                       n_nodes, 1, mode);
      }
      return;
    }
  }

  // -------- tier 3: atomic scatter --------
  {
    float* pre = (float*)d_ws;
    if (ws_size < (size_t)n_nodes * DOUT * 4) return;
    const int n4 = out_size / 4;
    zero_f4<<<2048, 256, 0, stream>>>((float4*)out, n4);
    for (int s = 0; s < n_supports; ++s) {
      gemm_xw<<<dim3(gemm_blocks, 1), 256, 0, stream>>>(x, W + (size_t)s * DIN * DOUT,
                                                        pre, n_nodes);
      spmm_atomic<<<2048, 256, 0, stream>>>(pre, esrc + (size_t)s * n_edges,
                                            edst + (size_t)s * n_edges,
                                            eval_ + (size_t)s * n_edges, out, n_edges);
    }
    relu_f4<<<2048, 256, 0, stream>>>((float4*)out, n4);
  }
}

// Round 7
// 190.162 us; speedup vs baseline: 7.5417x; 1.0536x over previous
//
#include <hip/hip_runtime.h>

#define DIN 128
#define DOUT 128
#define EPB 4096            // edges per block for count/partition
#define BKT 512             // nodes per bucket (dst >> 9)
#define PACK_BITS 19        // src_global bits; dst_low in bits 19..27
#define SRCG_MASK ((1u << PACK_BITS) - 1u)

typedef __attribute__((ext_vector_type(8))) short short8;
typedef __attribute__((ext_vector_type(4))) float f32x4;
typedef __attribute__((ext_vector_type(8))) unsigned short ushort8;

__device__ __forceinline__ unsigned short f2bf(float f) {
  unsigned int u = __float_as_uint(f);
  u += 0x7fffu + ((u >> 16) & 1u);   // round-to-nearest-even
  return (unsigned short)(u >> 16);
}

// ======================= W -> W^T bf16 (once, tiny) =======================
// W [s][k][n] fp32 -> wT [s][n][k] bf16. One block per support, LDS transpose.

__global__ __launch_bounds__(256) void wconvert(const float* __restrict__ W,
                                                unsigned short* __restrict__ wT) {
  __shared__ unsigned short buf[128][136];
  const int s = blockIdx.x;
  const float* Ws = W + (size_t)s * DIN * DOUT;
  unsigned short* wts = wT + (size_t)s * DIN * DOUT;
  const int tid = threadIdx.x;
#pragma unroll
  for (int i = 0; i < 16; ++i) {
    int e = tid + i * 256;
    int k = e >> 5, c = (e & 31) * 4;
    float4 v = *reinterpret_cast<const float4*>(&Ws[(size_t)k * DOUT + c]);
    buf[c][k] = f2bf(v.x); buf[c + 1][k] = f2bf(v.y);
    buf[c + 2][k] = f2bf(v.z); buf[c + 3][k] = f2bf(v.w);
  }
  __syncthreads();
#pragma unroll
  for (int i = 0; i < 8; ++i) {
    int e = tid + i * 256;
    int r = e >> 4, c = (e & 15) * 8;
    *reinterpret_cast<ushort8*>(&wts[(size_t)r * DIN + c]) =
        *reinterpret_cast<const ushort8*>(&buf[r][c]);
  }
}

// ======================= MFMA GEMM: pre[s] = bf16(x @ W[s]) =======================
// Operands loaded DIRECTLY from global (A: 32B k-contiguous fp32 per lane from x;
// B: 16B k-contiguous bf16 per lane from wT, L1/L2-resident). LDS only for C-stage.

__global__ __launch_bounds__(256) void gemm_mfma(const float* __restrict__ x,
                                                 const unsigned short* __restrict__ wT,
                                                 unsigned short* __restrict__ pre,
                                                 int n_nodes, int n_sup) {
  __shared__ unsigned short cst[128][136];

  const int tid = threadIdx.x;
  const int lane = tid & 63;
  const int w = tid >> 6;
  const int row0 = blockIdx.x * 128;
  const int alr = lane & 15;
  const int akg = lane >> 4;

  // A fragments: row = row0 + w*32 + mt*16 + alr, k = kc*32 + akg*8 + j
  short8 afrag[4][2];
#pragma unroll
  for (int kc = 0; kc < 4; ++kc)
#pragma unroll
    for (int mt = 0; mt < 2; ++mt) {
      int gr = row0 + w * 32 + mt * 16 + alr;
      short8 a = {0, 0, 0, 0, 0, 0, 0, 0};
      if (gr < n_nodes) {
        const float4* p =
            reinterpret_cast<const float4*>(&x[(size_t)gr * DIN + kc * 32 + akg * 8]);
        float4 v0 = p[0];
        float4 v1 = p[1];
        a[0] = (short)f2bf(v0.x); a[1] = (short)f2bf(v0.y);
        a[2] = (short)f2bf(v0.z); a[3] = (short)f2bf(v0.w);
        a[4] = (short)f2bf(v1.x); a[5] = (short)f2bf(v1.y);
        a[6] = (short)f2bf(v1.z); a[7] = (short)f2bf(v1.w);
      }
      afrag[kc][mt] = a;
    }

  for (int s = 0; s < n_sup; ++s) {
    const unsigned short* wts = wT + (size_t)s * DIN * DOUT;

    f32x4 acc[2][8];
#pragma unroll
    for (int mt = 0; mt < 2; ++mt)
#pragma unroll
      for (int nt = 0; nt < 8; ++nt) acc[mt][nt] = (f32x4){0.f, 0.f, 0.f, 0.f};

#pragma unroll
    for (int kc = 0; kc < 4; ++kc) {
      short8 bfrag[8];
#pragma unroll
      for (int nt = 0; nt < 8; ++nt)
        bfrag[nt] = *reinterpret_cast<const short8*>(
            &wts[(size_t)(nt * 16 + alr) * DIN + kc * 32 + akg * 8]);
#pragma unroll
      for (int mt = 0; mt < 2; ++mt)
#pragma unroll
        for (int nt = 0; nt < 8; ++nt)
          acc[mt][nt] = __builtin_amdgcn_mfma_f32_16x16x32_bf16(
              afrag[kc][mt], bfrag[nt], acc[mt][nt], 0, 0, 0);
    }

    __syncthreads();  // previous support's store-stage reads must be done
#pragma unroll
    for (int mt = 0; mt < 2; ++mt)
#pragma unroll
      for (int nt = 0; nt < 8; ++nt)
#pragma unroll
        for (int q = 0; q < 4; ++q)
          cst[w * 32 + mt * 16 + akg * 4 + q][nt * 16 + alr] = f2bf(acc[mt][nt][q]);
    __syncthreads();

    unsigned short* ps = pre + (size_t)s * n_nodes * DOUT;
#pragma unroll
    for (int i = 0; i < 8; ++i) {
      int e = tid + i * 256;
      int r = e >> 4;
      int c = (e & 15) * 8;
      int gr = row0 + r;
      if (gr < n_nodes)
        *reinterpret_cast<ushort8*>(&ps[(size_t)gr * DOUT + c]) =
            *reinterpret_cast<const ushort8*>(&cst[r][c]);
    }
  }
}

// ======================= fp32 fallback GEMM (tiers 2/3) =======================

__global__ __launch_bounds__(256) void gemm_xw(const float* __restrict__ x,
                                               const float* __restrict__ W,
                                               float* __restrict__ pre,
                                               int n_nodes) {
  __shared__ float xsf[128][33];
  __shared__ float wtf[32][129];
  const float* Ws = W + (size_t)blockIdx.y * DIN * DOUT;
  float* pres = pre + (size_t)blockIdx.y * n_nodes * DOUT;
  const int tid = threadIdx.x;
  const int row0 = blockIdx.x * 128;
  const int tcol = tid & 15;
  const int trow = tid >> 4;
  float acc[8][8];
#pragma unroll
  for (int i = 0; i < 8; ++i)
#pragma unroll
    for (int j = 0; j < 8; ++j) acc[i][j] = 0.f;
#pragma unroll 1
  for (int kk = 0; kk < DIN; kk += 32) {
#pragma unroll
    for (int i = 0; i < 4; ++i) {
      int e = tid + i * 256;
      int r = e >> 3, c = (e & 7) * 4;
      int gr = row0 + r;
      float4 v = make_float4(0.f, 0.f, 0.f, 0.f);
      if (gr < n_nodes)
        v = *reinterpret_cast<const float4*>(&x[(size_t)gr * DIN + kk + c]);
      xsf[r][c] = v.x; xsf[r][c + 1] = v.y; xsf[r][c + 2] = v.z; xsf[r][c + 3] = v.w;
    }
#pragma unroll
    for (int i = 0; i < 4; ++i) {
      int e = tid + i * 256;
      int k = e >> 5, c = (e & 31) * 4;
      float4 v = *reinterpret_cast<const float4*>(&Ws[(size_t)(kk + k) * DOUT + c]);
      wtf[k][c] = v.x; wtf[k][c + 1] = v.y; wtf[k][c + 2] = v.z; wtf[k][c + 3] = v.w;
    }
    __syncthreads();
#pragma unroll 4
    for (int k = 0; k < 32; ++k) {
      float a[8], b[8];
#pragma unroll
      for (int i = 0; i < 8; ++i) a[i] = xsf[trow * 8 + i][k];
#pragma unroll
      for (int j = 0; j < 8; ++j) b[j] = wtf[k][tcol + 16 * j];
#pragma unroll
      for (int i = 0; i < 8; ++i)
#pragma unroll
        for (int j = 0; j < 8; ++j) acc[i][j] = fmaf(a[i], b[j], acc[i][j]);
    }
    __syncthreads();
  }
#pragma unroll
  for (int i = 0; i < 8; ++i) {
    int gr = row0 + trow * 8 + i;
    if (gr < n_nodes) {
#pragma unroll
      for (int j = 0; j < 8; ++j)
        pres[(size_t)gr * DOUT + tcol + 16 * j] = acc[i][j];
    }
  }
}

// ======================= bucketed CSR build =======================

__global__ __launch_bounds__(256) void bucket_count(const int* __restrict__ dst_all,
                                                    int* __restrict__ bucket_cnt, int TE) {
  __shared__ int cnt[256];
  const int tid = threadIdx.x;
  cnt[tid] = 0;
  __syncthreads();
  const int beg = blockIdx.x * EPB;
  const int end = min(beg + EPB, TE);
  for (int i = beg + tid; i < end; i += 256) atomicAdd(&cnt[dst_all[i] >> 9], 1);
  __syncthreads();
  int c = cnt[tid];
  if (c) atomicAdd(&bucket_cnt[tid], c);
}

__global__ __launch_bounds__(256) void bucket_scan(const int* __restrict__ bucket_cnt,
                                                   int* __restrict__ bucket_base,
                                                   int* __restrict__ bucket_cursor,
                                                   int NB, int TE) {
  __shared__ int tmp[256];
  const int tid = threadIdx.x;
  int v = (tid < NB) ? bucket_cnt[tid] : 0;
  tmp[tid] = v;
  __syncthreads();
#pragma unroll
  for (int d = 1; d < 256; d <<= 1) {
    int t = (tid >= d) ? tmp[tid - d] : 0;
    __syncthreads();
    tmp[tid] += t;
    __syncthreads();
  }
  int excl = tmp[tid] - v;
  if (tid < NB) {
    bucket_base[tid] = excl;
    bucket_cursor[tid] = excl;
  }
  if (tid == 0) bucket_base[NB] = TE;
}

__global__ __launch_bounds__(256) void partition_edges(const int* __restrict__ src_all,
                                                       const int* __restrict__ dst_all,
                                                       const float* __restrict__ val_all,
                                                       int* __restrict__ bucket_cursor,
                                                       int2* __restrict__ part,
                                                       int TE, int n_nodes, int n_edges) {
  __shared__ int cnt[256];
  __shared__ int base_l[256];
  const int tid = threadIdx.x;
  const int beg = blockIdx.x * EPB;
  const int end = min(beg + EPB, TE);

  cnt[tid] = 0;
  __syncthreads();
  for (int i = beg + tid; i < end; i += 256) atomicAdd(&cnt[dst_all[i] >> 9], 1);
  __syncthreads();

  int c = cnt[tid];
  int mybase = (c > 0) ? atomicAdd(&bucket_cursor[tid], c) : 0;
  __syncthreads();
  base_l[tid] = mybase;
  cnt[tid] = 0;
  __syncthreads();

  for (int i = beg + tid; i < end; i += 256) {
    int d = dst_all[i];
    int b = d >> 9;
    int r = atomicAdd(&cnt[b], 1);
    int s = i / n_edges;
    unsigned key = (unsigned)(s * n_nodes + src_all[i]) |
                   ((unsigned)(d & (BKT - 1)) << PACK_BITS);
    part[base_l[b] + r] = make_int2((int)key, __float_as_int(val_all[i]));
  }
}

__global__ __launch_bounds__(256) void csr_build(const int2* __restrict__ part,
                                                 const int* __restrict__ bucket_base,
                                                 int2* __restrict__ csr,
                                                 int* __restrict__ row_off,
                                                 int n_nodes, int TE) {
  __shared__ int cnt[BKT];
  __shared__ int off_s[BKT];
  __shared__ int tmp[256];
  const int b = blockIdx.x;
  const int tid = threadIdx.x;
  const int bb = bucket_base[b];
  const int be = bucket_base[b + 1];

  cnt[tid] = 0;
  cnt[tid + 256] = 0;
  __syncthreads();
  for (int j = bb + tid; j < be; j += 256)
    atomicAdd(&cnt[((unsigned)part[j].x) >> PACK_BITS], 1);
  __syncthreads();

  int s2 = cnt[2 * tid] + cnt[2 * tid + 1];
  tmp[tid] = s2;
  __syncthreads();
#pragma unroll
  for (int d = 1; d < 256; d <<= 1) {
    int t = (tid >= d) ? tmp[tid - d] : 0;
    __syncthreads();
    tmp[tid] += t;
    __syncthreads();
  }
  int excl2 = tmp[tid] - s2;
  off_s[2 * tid] = excl2;
  off_s[2 * tid + 1] = excl2 + cnt[2 * tid];
  __syncthreads();

#pragma unroll
  for (int k = tid; k < BKT; k += 256) {
    int node = b * BKT + k;
    if (node < n_nodes) row_off[node] = bb + off_s[k];
  }
  cnt[tid] = off_s[tid];
  cnt[tid + 256] = off_s[tid + 256];
  __syncthreads();

  for (int j = bb + tid; j < be; j += 256) {
    int2 e = part[j];
    int dl = ((unsigned)e.x) >> PACK_BITS;
    int p = bb + atomicAdd(&cnt[dl], 1);
    csr[p] = e;
  }
  if (b == 0 && tid == 0) row_off[n_nodes] = TE;
}

// ======================= gather: 8 edges in flight per wave =======================

__global__ __launch_bounds__(256) void spmm_gather8(const unsigned short* __restrict__ pre,
                                                    const int2* __restrict__ csr,
                                                    const int* __restrict__ row_off,
                                                    float* __restrict__ out, int n_nodes) {
  const int lane = threadIdx.x & 63;
  const int g = lane >> 3;
  const int t = lane & 7;
  const int wave = blockIdx.x * (blockDim.x >> 6) + (threadIdx.x >> 6);
  const int nwaves = gridDim.x * (blockDim.x >> 6);

  for (int n = wave; n < n_nodes; n += nwaves) {
    const int beg = row_off[n];
    const int end = row_off[n + 1];
    float acc[16];
#pragma unroll
    for (int k = 0; k < 16; ++k) acc[k] = 0.f;

    for (int j = beg + g; j < end; j += 8) {
      const int2 e = csr[j];
      const float v = __int_as_float(e.y);
      const unsigned srcg = ((unsigned)e.x) & SRCG_MASK;
      const ushort8* pr =
          reinterpret_cast<const ushort8*>(&pre[(size_t)srcg * DOUT + t * 16]);
      ushort8 p0 = pr[0];
      ushort8 p1 = pr[1];
#pragma unroll
      for (int k = 0; k < 8; ++k) {
        acc[k]     = fmaf(v, __uint_as_float((unsigned int)(unsigned short)p0[k] << 16), acc[k]);
        acc[8 + k] = fmaf(v, __uint_as_float((unsigned int)(unsigned short)p1[k] << 16), acc[8 + k]);
      }
    }

#pragma unroll
    for (int d = 8; d <= 32; d <<= 1)
#pragma unroll
      for (int k = 0; k < 16; ++k) acc[k] += __shfl_xor(acc[k], d, 64);

    float r0 = 0.f, r1 = 0.f;
#pragma unroll
    for (int gg = 0; gg < 8; ++gg)
      if (gg == g) { r0 = acc[gg * 2]; r1 = acc[gg * 2 + 1]; }
    r0 = fmaxf(r0, 0.f);
    r1 = fmaxf(r1, 0.f);
    *reinterpret_cast<float2*>(&out[(size_t)n * DOUT + t * 16 + g * 2]) =
        make_float2(r0, r1);
  }
}

// ======================= tier-2/3 fallback kernels =======================

__global__ __launch_bounds__(256) void edge_hist(const int* __restrict__ dst_base,
                                                 int* __restrict__ counts,
                                                 int n_edges, int n_nodes) {
  int i = blockIdx.x * blockDim.x + threadIdx.x;
  int s = blockIdx.y;
  if (i < n_edges) atomicAdd(&counts[s * n_nodes + dst_base[(size_t)s * n_edges + i]], 1);
}

__global__ __launch_bounds__(256) void scan_local(const int* __restrict__ counts,
                                                  int* __restrict__ row_off,
                                                  int* __restrict__ partials, int n) {
  __shared__ int tmp[256];
  const int tid = threadIdx.x;
  const int base = blockIdx.x * 2048 + tid * 8;
  int v[8];
#pragma unroll
  for (int i = 0; i < 8; ++i) v[i] = (base + i < n) ? counts[base + i] : 0;
  int s = 0;
#pragma unroll
  for (int i = 0; i < 8; ++i) s += v[i];
  tmp[tid] = s;
  __syncthreads();
#pragma unroll
  for (int d = 1; d < 256; d <<= 1) {
    int t = (tid >= d) ? tmp[tid - d] : 0;
    __syncthreads();
    tmp[tid] += t;
    __syncthreads();
  }
  int p = tmp[tid] - s;
#pragma unroll
  for (int i = 0; i < 8; ++i) {
    if (base + i < n) row_off[base + i] = p;
    p += v[i];
  }
  if (tid == 255) partials[blockIdx.x] = tmp[255];
}

__global__ __launch_bounds__(256) void scan_partials_k(int* __restrict__ partials, int nblk) {
  __shared__ int tmp[256];
  const int tid = threadIdx.x;
  int v = (tid < nblk) ? partials[tid] : 0;
  tmp[tid] = v;
  __syncthreads();
#pragma unroll
  for (int d = 1; d < 256; d <<= 1) {
    int t = (tid >= d) ? tmp[tid - d] : 0;
    __syncthreads();
    tmp[tid] += t;
    __syncthreads();
  }
  if (tid < nblk) partials[tid] = tmp[tid] - v;
}

__global__ __launch_bounds__(256) void scan_finish(int* __restrict__ row_off,
                                                   int* __restrict__ cursor,
                                                   const int* __restrict__ partials,
                                                   int n, int total_edges) {
  const int off = partials[blockIdx.x];
  const int base = blockIdx.x * 2048 + threadIdx.x * 8;
#pragma unroll
  for (int i = 0; i < 8; ++i) {
    int idx = base + i;
    if (idx < n) {
      int v = row_off[idx] + off;
      row_off[idx] = v;
      cursor[idx] = v;
    }
  }
  if (blockIdx.x == 0 && threadIdx.x == 0) row_off[n] = total_edges;
}

__global__ __launch_bounds__(256) void edge_fill(const int* __restrict__ src_base,
                                                 const int* __restrict__ dst_base,
                                                 const float* __restrict__ val_base,
                                                 int* __restrict__ cursor,
                                                 int2* __restrict__ csr,
                                                 int n_edges, int n_nodes) {
  int i = blockIdx.x * blockDim.x + threadIdx.x;
  int s = blockIdx.y;
  if (i < n_edges) {
    size_t gi = (size_t)s * n_edges + i;
    int d = dst_base[gi];
    int pos = atomicAdd(&cursor[s * n_nodes + d], 1);
    csr[pos] = make_int2(src_base[gi], __float_as_int(val_base[gi]));
  }
}

__global__ __launch_bounds__(256) void spmm_gather(const float* __restrict__ pre,
                                                   const int2* __restrict__ csr,
                                                   const int* __restrict__ row_off,
                                                   float* __restrict__ out,
                                                   int n_nodes, int n_sup, int mode) {
  const int lane = threadIdx.x & 63;
  const int wave = blockIdx.x * (blockDim.x >> 6) + (threadIdx.x >> 6);
  const int nwaves = gridDim.x * (blockDim.x >> 6);
  for (int n = wave; n < n_nodes; n += nwaves) {
    float ax = 0.f, ay = 0.f;
    float2* o = reinterpret_cast<float2*>(&out[(size_t)n * DOUT + lane * 2]);
    if (mode & 1) { float2 prev = *o; ax = prev.x; ay = prev.y; }
    for (int s = 0; s < n_sup; ++s) {
      const float* ps = pre + (size_t)s * n_nodes * DOUT;
      const int row = s * n_nodes + n;
      const int beg = row_off[row];
      const int end = row_off[row + 1];
      for (int j = beg; j < end; ++j) {
        const int2 e = csr[j];
        const float v = __int_as_float(e.y);
        const float2 p = *reinterpret_cast<const float2*>(&ps[(size_t)e.x * DOUT + lane * 2]);
        ax = fmaf(v, p.x, ax);
        ay = fmaf(v, p.y, ay);
      }
    }
    if (mode & 2) { ax = fmaxf(ax, 0.f); ay = fmaxf(ay, 0.f); }
    *o = make_float2(ax, ay);
  }
}

__global__ __launch_bounds__(256) void zero_f4(float4* __restrict__ p, int n4) {
  int i = blockIdx.x * blockDim.x + threadIdx.x;
  int stride = gridDim.x * blockDim.x;
  float4 z = make_float4(0.f, 0.f, 0.f, 0.f);
  for (; i < n4; i += stride) p[i] = z;
}

__global__ __launch_bounds__(256) void relu_f4(float4* __restrict__ p, int n4) {
  int i = blockIdx.x * blockDim.x + threadIdx.x;
  int stride = gridDim.x * blockDim.x;
  for (; i < n4; i += stride) {
    float4 v = p[i];
    v.x = fmaxf(v.x, 0.f); v.y = fmaxf(v.y, 0.f);
    v.z = fmaxf(v.z, 0.f); v.w = fmaxf(v.w, 0.f);
    p[i] = v;
  }
}

__global__ __launch_bounds__(256) void spmm_atomic(const float* __restrict__ pre,
                                                   const int* __restrict__ src,
                                                   const int* __restrict__ dst,
                                                   const float* __restrict__ val,
                                                   float* __restrict__ out,
                                                   int n_edges) {
  const int lane = threadIdx.x & 63;
  const int wave = blockIdx.x * (blockDim.x >> 6) + (threadIdx.x >> 6);
  const int nwaves = gridDim.x * (blockDim.x >> 6);
  for (int e = wave; e < n_edges; e += nwaves) {
    int s = src[e];
    int d = dst[e];
    float v = val[e];
    const float2 p = *reinterpret_cast<const float2*>(&pre[(size_t)s * DOUT + lane * 2]);
    float* o = &out[(size_t)d * DOUT + lane * 2];
    atomicAdd(o, v * p.x);
    atomicAdd(o + 1, v * p.y);
  }
}

// ======================= host launch =======================

static inline size_t align_up(size_t v, size_t a) { return (v + a - 1) & ~(a - 1); }

extern "C" void kernel_launch(void* const* d_in, const int* in_sizes, int n_in,
                              void* d_out, int out_size, void* d_ws, size_t ws_size,
                              hipStream_t stream) {
  const float* x     = (const float*)d_in[0];
  const float* W     = (const float*)d_in[1];
  const int*   esrc  = (const int*)d_in[2];
  const int*   edst  = (const int*)d_in[3];
  const float* eval_ = (const float*)d_in[4];
  float* out = (float*)d_out;

  const int n_nodes    = in_sizes[0] / DIN;
  const int n_supports = in_sizes[1] / (DIN * DOUT);
  const int n_edges    = in_sizes[2] / n_supports;

  const int gemm_blocks = (n_nodes + 127) / 128;
  const int edge_blocks = (n_edges + 255) / 256;
  const int gather_blocks = (n_nodes + 3) / 4;

  // -------- tier 1: direct-operand MFMA GEMM + bucketed CSR + 8-way gather --------
  {
    const int NR = n_supports * n_nodes;
    const int TE = n_supports * n_edges;
    const int NB = (n_nodes + BKT - 1) / BKT;
    const int eb = (TE + EPB - 1) / EPB;
    char* w = (char*)d_ws;
    size_t off = 0;
    unsigned short* pre3 = (unsigned short*)(w + off); off += align_up((size_t)NR * DOUT * 2, 256);
    unsigned short* wT = (unsigned short*)(w + off);   off += align_up((size_t)n_supports * DIN * DOUT * 2, 256);
    int* row_off = (int*)(w + off);      off += align_up((size_t)(n_nodes + 1) * 4, 256);
    int2* part = (int2*)(w + off);       off += align_up((size_t)TE * 8, 256);
    int2* csr = (int2*)(w + off);        off += align_up((size_t)TE * 8, 256);
    int* bucket_cnt = (int*)(w + off);   off += align_up(256 * 4, 256);
    int* bucket_base = (int*)(w + off);  off += align_up(257 * 4, 256);
    int* bucket_cur = (int*)(w + off);   off += align_up(256 * 4, 256);

    const bool packable = (size_t)n_supports * n_nodes < (1u << PACK_BITS);

    if (off <= ws_size && NB <= 256 && packable) {
      wconvert<<<n_supports, 256, 0, stream>>>(W, wT);
      gemm_mfma<<<gemm_blocks, 256, 0, stream>>>(x, wT, pre3, n_nodes, n_supports);
      hipMemsetAsync(bucket_cnt, 0, 256 * 4, stream);
      bucket_count<<<eb, 256, 0, stream>>>(edst, bucket_cnt, TE);
      bucket_scan<<<1, 256, 0, stream>>>(bucket_cnt, bucket_base, bucket_cur, NB, TE);
      partition_edges<<<eb, 256, 0, stream>>>(esrc, edst, eval_, bucket_cur, part,
                                              TE, n_nodes, n_edges);
      csr_build<<<NB, 256, 0, stream>>>(part, bucket_base, csr, row_off, n_nodes, TE);
      spmm_gather8<<<gather_blocks, 256, 0, stream>>>(pre3, csr, row_off, out, n_nodes);
      return;
    }
  }

  // -------- tier 2: fp32 per-support CSR gather --------
  {
    const int scan_blocks = (n_nodes + 2047) / 2048;
    char* w = (char*)d_ws;
    size_t off = 0;
    float* pre = (float*)(w + off);    off += align_up((size_t)n_nodes * DOUT * 4, 256);
    int* row_off = (int*)(w + off);    off += align_up((size_t)(n_nodes + 1) * 4, 256);
    int* cursor = (int*)(w + off);     off += align_up((size_t)n_nodes * 4, 256);
    int2* csr = (int2*)(w + off);      off += align_up((size_t)n_edges * 8, 256);
    int* partials = (int*)(w + off);   off += align_up(1024 * 4, 256);

    if (off <= ws_size && scan_blocks <= 256) {
      for (int s = 0; s < n_supports; ++s) {
        const int* src = esrc + (size_t)s * n_edges;
        const int* dst = edst + (size_t)s * n_edges;
        const float* val = eval_ + (size_t)s * n_edges;
        gemm_xw<<<dim3(gemm_blocks, 1), 256, 0, stream>>>(x, W + (size_t)s * DIN * DOUT,
                                                          pre, n_nodes);
        hipMemsetAsync(cursor, 0, (size_t)n_nodes * 4, stream);
        edge_hist<<<dim3(edge_blocks, 1), 256, 0, stream>>>(dst, cursor, n_edges, n_nodes);
        scan_local<<<scan_blocks, 256, 0, stream>>>(cursor, row_off, partials, n_nodes);
        scan_partials_k<<<1, 256, 0, stream>>>(partials, scan_blocks);
        scan_finish<<<scan_blocks, 256, 0, stream>>>(row_off, cursor, partials, n_nodes, n_edges);
        edge_fill<<<dim3(edge_blocks, 1), 256, 0, stream>>>(src, dst, val, cursor, csr,
                                                            n_edges, n_nodes);
        int mode = (s == 0) ? 0 : 1;
        if (s == n_supports - 1) mode |= 2;
        spmm_gather<<<gather_blocks, 256, 0, stream>>>(pre, csr, row_off, out,
                                                       n_nodes, 1, mode);
      }
      return;
    }
  }

  // -------- tier 3: atomic scatter --------
  {
    float* pre = (float*)d_ws;
    if (ws_size < (size_t)n_nodes * DOUT * 4) return;
    const int n4 = out_size / 4;
    zero_f4<<<2048, 256, 0, stream>>>((float4*)out, n4);
    for (int s = 0; s < n_supports; ++s) {
      gemm_xw<<<dim3(gemm_blocks, 1), 256, 0, stream>>>(x, W + (size_t)s * DIN * DOUT,
                                                        pre, n_nodes);
      spmm_atomic<<<2048, 256, 0, stream>>>(pre, esrc + (size_t)s * n_edges,
                                            edst + (size_t)s * n_edges,
                                            eval_ + (size_t)s * n_edges, out, n_edges);
    }
    relu_f4<<<2048, 256, 0, stream>>>((float4*)out, n4);
  }
}